// Round 3
// baseline (336.452 us; speedup 1.0000x reference)
//
#include <hip/hip_runtime.h>

constexpr int FIN = 512;
constexpr int FH  = 128;
constexpr int FO  = 64;

typedef short short8 __attribute__((ext_vector_type(8)));
typedef float f32x4 __attribute__((ext_vector_type(4)));

__device__ __forceinline__ unsigned short f2bf(float f) {
    unsigned u = __float_as_uint(f);
    u += 0x7fffu + ((u >> 16) & 1u);   // RNE
    return (unsigned short)(u >> 16);
}
__device__ __forceinline__ float bf2f(unsigned short h) {
    return __uint_as_float((unsigned)h << 16);
}

// ---------------- weight pre-conversion ----------------

__global__ void convw1_kernel(const float* __restrict__ W, unsigned short* __restrict__ Wb,
                              int n4) {
    int i = blockIdx.x * blockDim.x + threadIdx.x;
    if (i < n4) {
        float4 v = ((const float4*)W)[i];
        ushort4 p;
        p.x = f2bf(v.x); p.y = f2bf(v.y); p.z = f2bf(v.z); p.w = f2bf(v.w);
        ((ushort4*)Wb)[i] = p;
    }
}

// pack Wmu (rows 0-63) + Wlg (rows 64-127) into [128][128], split hi/lo bf16
__global__ void convw2_kernel(const float* __restrict__ Wmu, const float* __restrict__ Wlg,
                              unsigned short* __restrict__ Wh, unsigned short* __restrict__ Wl) {
    int i = blockIdx.x * blockDim.x + threadIdx.x;  // 0..16383
    if (i < 128 * 128) {
        int r = i >> 7, c = i & 127;
        float f = (r < 64) ? Wmu[r * 128 + c] : Wlg[(r - 64) * 128 + c];
        unsigned short h = f2bf(f);
        Wh[i] = h;
        Wl[i] = f2bf(f - bf2f(h));
    }
}

// ---------------- degree / normalization ----------------

__global__ void count_kernel(const int* __restrict__ dst, int* __restrict__ cnt, int E) {
    int i = blockIdx.x * blockDim.x + threadIdx.x;
    if (i < E) atomicAdd(&cnt[dst[i]], 1);
}

__global__ void dinv_kernel(const int* __restrict__ cnt, float* __restrict__ dinv, int n) {
    int i = blockIdx.x * blockDim.x + threadIdx.x;
    if (i < n) dinv[i] = rsqrtf((float)(cnt[i] + 1));  // deg = in-degree + self-loop
}

// ---------------- exclusive scan (3 kernels, 1024 elems/block) ----------------

__global__ void scan1_kernel(const int* __restrict__ cnt, int* __restrict__ offs,
                             int* __restrict__ bsum, int n) {
    __shared__ int sdata[256];
    int t = threadIdx.x;
    int base = blockIdx.x * 1024 + t * 4;
    int4 c = make_int4(0, 0, 0, 0);
    if (base + 3 < n) {
        c = *(const int4*)(cnt + base);
    } else {
        if (base + 0 < n) c.x = cnt[base + 0];
        if (base + 1 < n) c.y = cnt[base + 1];
        if (base + 2 < n) c.z = cnt[base + 2];
        if (base + 3 < n) c.w = cnt[base + 3];
    }
    int s0 = c.x + c.y + c.z + c.w;
    sdata[t] = s0;
    __syncthreads();
    for (int off = 1; off < 256; off <<= 1) {
        int v = (t >= off) ? sdata[t - off] : 0;
        __syncthreads();
        sdata[t] += v;
        __syncthreads();
    }
    int excl = sdata[t] - s0;
    if (t == 255) bsum[blockIdx.x] = sdata[255];
    if (base + 0 < n) offs[base + 0] = excl;
    if (base + 1 < n) offs[base + 1] = excl + c.x;
    if (base + 2 < n) offs[base + 2] = excl + c.x + c.y;
    if (base + 3 < n) offs[base + 3] = excl + c.x + c.y + c.z;
}

__global__ void scan2_kernel(int* __restrict__ bsum, int nb) {
    __shared__ int sdata[256];
    int t = threadIdx.x;
    int v = (t < nb) ? bsum[t] : 0;
    sdata[t] = v;
    __syncthreads();
    for (int off = 1; off < 256; off <<= 1) {
        int u = (t >= off) ? sdata[t - off] : 0;
        __syncthreads();
        sdata[t] += u;
        __syncthreads();
    }
    if (t < nb) bsum[t] = sdata[t] - v;  // exclusive
}

__global__ void scan3_kernel(int* __restrict__ offs, const int* __restrict__ bsum,
                             int n, int E) {
    int i = blockIdx.x * blockDim.x + threadIdx.x;
    if (i < n) offs[i] += bsum[i >> 10];
    if (i == 0) offs[n] = E;
}

// ---------------- CSR fill (counting sort by dst) ----------------

__global__ void fill_kernel(const int* __restrict__ src, const int* __restrict__ dst,
                            const float* __restrict__ dinv, const int* __restrict__ offs,
                            int* __restrict__ cursor, int2* __restrict__ esort, int E) {
    int i = blockIdx.x * blockDim.x + threadIdx.x;
    if (i < E) {
        int s = src[i];
        int d = dst[i];
        int pos = offs[d] + atomicAdd(&cursor[d], 1);
        float w = dinv[s] * dinv[d];
        esort[pos] = make_int2(s, __float_as_int(w));
    }
}

// ---------------- SpMM gather: out[i] = dinv[i]^2*h[i] + sum_e norm_e * h[src_e] ---

__global__ void spmm_kernel(const float* __restrict__ hin, const int* __restrict__ offs,
                            const int2* __restrict__ esort, const float* __restrict__ dinv,
                            const float* __restrict__ bias, float* __restrict__ hout,
                            int n, int relu) {
    int gid = blockIdx.x * blockDim.x + threadIdx.x;
    int node = gid >> 6;            // one 64-lane wave per node
    int lane = threadIdx.x & 63;    // lane handles channels 2*lane, 2*lane+1
    if (node >= n) return;
    const float2* h2 = (const float2*)hin;
    float di = dinv[node];
    float2 hv = h2[(size_t)node * 64 + lane];
    float ax = di * di * hv.x;
    float ay = di * di * hv.y;
    int p = offs[node];
    int end = offs[node + 1];
    for (; p + 4 <= end; p += 4) {
        int2 e0 = esort[p + 0];
        int2 e1 = esort[p + 1];
        int2 e2 = esort[p + 2];
        int2 e3 = esort[p + 3];
        float2 v0 = h2[(size_t)e0.x * 64 + lane];
        float2 v1 = h2[(size_t)e1.x * 64 + lane];
        float2 v2 = h2[(size_t)e2.x * 64 + lane];
        float2 v3 = h2[(size_t)e3.x * 64 + lane];
        float w0 = __int_as_float(e0.y), w1 = __int_as_float(e1.y);
        float w2 = __int_as_float(e2.y), w3 = __int_as_float(e3.y);
        ax = fmaf(w0, v0.x, ax); ay = fmaf(w0, v0.y, ay);
        ax = fmaf(w1, v1.x, ax); ay = fmaf(w1, v1.y, ay);
        ax = fmaf(w2, v2.x, ax); ay = fmaf(w2, v2.y, ay);
        ax = fmaf(w3, v3.x, ax); ay = fmaf(w3, v3.y, ay);
    }
    for (; p < end; ++p) {
        int2 e = esort[p];
        float2 v = h2[(size_t)e.x * 64 + lane];
        float w = __int_as_float(e.y);
        ax = fmaf(w, v.x, ax); ay = fmaf(w, v.y, ay);
    }
    if (bias) {
        float2 b = ((const float2*)bias)[lane];
        ax += b.x; ay += b.y;
    }
    if (relu) { ax = fmaxf(ax, 0.f); ay = fmaxf(ay, 0.f); }
    float2 o; o.x = ax; o.y = ay;
    ((float2*)hout)[(size_t)node * 64 + lane] = o;
}

// ---------------- GEMM1: h[M,128] = X[M,512] @ W1b[128,512]^T  (bf16 MFMA) -------
// Barrier-free, LDS-free. One wave = 16 rows x 128 cols. Fragments loaded
// directly from global: A row = lane&15, k = (lane>>4)*8..+8 (2x float4 + cvt);
// B from pre-converted bf16 W (L2-resident stream).

__global__ __launch_bounds__(256) void gemm1_kernel(
    const float* __restrict__ X, const unsigned short* __restrict__ Wb,
    float* __restrict__ out, int M) {
    int tid = threadIdx.x;
    int lane = tid & 63;
    int wid = tid >> 6;
    int fr = lane & 15, fq = lane >> 4;
    int row0 = blockIdx.x * 64 + wid * 16;   // this wave's 16-row strip
    int arow = row0 + fr;
    bool aok = arow < M;
    const float* ap = X + (size_t)arow * FIN + fq * 8;

    const unsigned short* bp[8];
    #pragma unroll
    for (int c = 0; c < 8; ++c)
        bp[c] = Wb + (size_t)(c * 16 + fr) * FIN + fq * 8;

    f32x4 acc[8] = {};

    #pragma unroll 4
    for (int k0 = 0; k0 < FIN; k0 += 32) {
        float4 v0 = make_float4(0.f, 0.f, 0.f, 0.f), v1 = v0;
        if (aok) {
            v0 = *(const float4*)(ap + k0);
            v1 = *(const float4*)(ap + k0 + 4);
        }
        short8 af;
        af[0] = (short)f2bf(v0.x); af[1] = (short)f2bf(v0.y);
        af[2] = (short)f2bf(v0.z); af[3] = (short)f2bf(v0.w);
        af[4] = (short)f2bf(v1.x); af[5] = (short)f2bf(v1.y);
        af[6] = (short)f2bf(v1.z); af[7] = (short)f2bf(v1.w);
        #pragma unroll
        for (int c = 0; c < 8; ++c) {
            short8 bfrag = *(const short8*)(bp[c] + k0);
            acc[c] = __builtin_amdgcn_mfma_f32_16x16x32_bf16(af, bfrag, acc[c], 0, 0, 0);
        }
    }

    // C/D: col = lane&15 (fr), row = fq*4 + j
    #pragma unroll
    for (int c = 0; c < 8; ++c) {
        #pragma unroll
        for (int j = 0; j < 4; ++j) {
            int row = row0 + fq * 4 + j;
            if (row < M) out[(size_t)row * FH + c * 16 + fr] = acc[c][j];
        }
    }
}

// ---------------- GEMM2: mu/logstd[M,64] = ah2[M,128] @ W^T + b  (bf16x3 MFMA) ----
// Same barrier-free structure; A split a=ah+al, B split in Wh/Wl; three MFMAs
// per fragment give ~fp32 accuracy.

__global__ __launch_bounds__(256) void gemm2_kernel(
    const float* __restrict__ X,
    const unsigned short* __restrict__ Wh, const unsigned short* __restrict__ Wl,
    float* __restrict__ outA, float* __restrict__ outB,
    const float* __restrict__ biasA, const float* __restrict__ biasB, int M) {
    int tid = threadIdx.x;
    int lane = tid & 63;
    int wid = tid >> 6;
    int fr = lane & 15, fq = lane >> 4;
    int row0 = blockIdx.x * 64 + wid * 16;
    int arow = row0 + fr;
    bool aok = arow < M;
    const float* ap = X + (size_t)arow * FH + fq * 8;

    const unsigned short* bph[8];
    const unsigned short* bpl[8];
    #pragma unroll
    for (int c = 0; c < 8; ++c) {
        size_t o = (size_t)(c * 16 + fr) * FH + fq * 8;
        bph[c] = Wh + o;
        bpl[c] = Wl + o;
    }

    f32x4 acc[8] = {};

    #pragma unroll 2
    for (int k0 = 0; k0 < FH; k0 += 32) {
        float4 v0 = make_float4(0.f, 0.f, 0.f, 0.f), v1 = v0;
        if (aok) {
            v0 = *(const float4*)(ap + k0);
            v1 = *(const float4*)(ap + k0 + 4);
        }
        float a[8] = {v0.x, v0.y, v0.z, v0.w, v1.x, v1.y, v1.z, v1.w};
        short8 ah, al;
        #pragma unroll
        for (int i = 0; i < 8; ++i) {
            unsigned short h = f2bf(a[i]);
            ah[i] = (short)h;
            al[i] = (short)f2bf(a[i] - bf2f(h));
        }
        #pragma unroll
        for (int c = 0; c < 8; ++c) {
            short8 bh = *(const short8*)(bph[c] + k0);
            short8 bl = *(const short8*)(bpl[c] + k0);
            acc[c] = __builtin_amdgcn_mfma_f32_16x16x32_bf16(ah, bh, acc[c], 0, 0, 0);
            acc[c] = __builtin_amdgcn_mfma_f32_16x16x32_bf16(al, bh, acc[c], 0, 0, 0);
            acc[c] = __builtin_amdgcn_mfma_f32_16x16x32_bf16(ah, bl, acc[c], 0, 0, 0);
        }
    }

    #pragma unroll
    for (int c = 0; c < 8; ++c) {
        float* outp = (c < 4) ? outA : outB;
        const float* bp = (c < 4) ? biasA : biasB;
        int col = (c & 3) * 16 + fr;
        float bv = bp[col];
        #pragma unroll
        for (int j = 0; j < 4; ++j) {
            int row = row0 + fq * 4 + j;
            if (row < M) outp[(size_t)row * FO + col] = acc[c][j] + bv;
        }
    }
}

// ---------------- launch ----------------

extern "C" void kernel_launch(void* const* d_in, const int* in_sizes, int n_in,
                              void* d_out, int out_size, void* d_ws, size_t ws_size,
                              hipStream_t stream) {
    const float* x   = (const float*)d_in[0];
    const int*   ei  = (const int*)d_in[1];
    const float* W1  = (const float*)d_in[2];
    const float* b1  = (const float*)d_in[3];
    const float* Wmu = (const float*)d_in[4];
    const float* bmu = (const float*)d_in[5];
    const float* Wlg = (const float*)d_in[6];
    const float* blg = (const float*)d_in[7];

    const int n = in_sizes[0] / FIN;   // 50000
    const int E = in_sizes[1] / 2;     // 800000
    const int* src = ei;
    const int* dst = ei + E;

    char* ws = (char*)d_ws;
    size_t off = 0;
    auto alloc = [&](size_t bytes) -> void* {
        void* p = ws + off;
        off = (off + bytes + 255) & ~((size_t)255);
        return p;
    };
    int*   cnt    = (int*)  alloc((size_t)n * 4);
    int*   offs   = (int*)  alloc((size_t)(n + 1) * 4);
    int*   cursor = (int*)  alloc((size_t)n * 4);
    int*   bsum   = (int*)  alloc(1024);
    float* dinv   = (float*)alloc((size_t)n * 4);
    int2*  esort  = (int2*) alloc((size_t)E * 8);
    float* h      = (float*)alloc((size_t)n * FH * 4);
    float* h1     = (float*)alloc((size_t)n * FH * 4);
    unsigned short* W1b = (unsigned short*)alloc((size_t)FH * FIN * 2);
    unsigned short* W2h = (unsigned short*)alloc((size_t)FH * FH * 2);
    unsigned short* W2l = (unsigned short*)alloc((size_t)FH * FH * 2);

    hipMemsetAsync(cnt, 0, (size_t)n * 4, stream);
    hipMemsetAsync(cursor, 0, (size_t)n * 4, stream);

    // weight conversions (independent of graph work)
    convw1_kernel<<<(FH * FIN / 4 + 255) / 256, 256, 0, stream>>>(W1, W1b, FH * FIN / 4);
    convw2_kernel<<<(FH * FH + 255) / 256, 256, 0, stream>>>(Wmu, Wlg, W2h, W2l);

    count_kernel<<<(E + 255) / 256, 256, 0, stream>>>(dst, cnt, E);
    dinv_kernel<<<(n + 255) / 256, 256, 0, stream>>>(cnt, dinv, n);

    int nb = (n + 1023) / 1024;  // 49
    scan1_kernel<<<nb, 256, 0, stream>>>(cnt, offs, bsum, n);
    scan2_kernel<<<1, 256, 0, stream>>>(bsum, nb);
    scan3_kernel<<<(n + 255) / 256, 256, 0, stream>>>(offs, bsum, n, E);

    fill_kernel<<<(E + 255) / 256, 256, 0, stream>>>(src, dst, dinv, offs, cursor, esort, E);

    // layer 1: h = x @ W1^T   (bf16 MFMA, barrier-free)
    gemm1_kernel<<<(n + 63) / 64, 256, 0, stream>>>(x, W1b, h, n);
    // h1 = relu(A_norm @ h + b1)
    spmm_kernel<<<(n + 3) / 4, 256, 0, stream>>>(h, offs, esort, dinv, b1, h1, n, 1);
    // ah2 = A_norm @ h1 (reuse h buffer)
    spmm_kernel<<<(n + 3) / 4, 256, 0, stream>>>(h1, offs, esort, dinv, nullptr, h, n, 0);
    // mu / logstd = ah2 @ W^T + b   (bf16x3 MFMA)
    float* outmu = (float*)d_out;
    float* outlg = outmu + (size_t)n * FO;
    gemm2_kernel<<<(n + 63) / 64, 256, 0, stream>>>(
        h, W2h, W2l, outmu, outlg, bmu, blg, n);
}

// Round 4
// 302.688 us; speedup vs baseline: 1.1115x; 1.1115x over previous
//
#include <hip/hip_runtime.h>

constexpr int FIN = 512;
constexpr int FH  = 128;
constexpr int FO  = 64;

typedef short short8 __attribute__((ext_vector_type(8)));
typedef float f32x4 __attribute__((ext_vector_type(4)));

__device__ __forceinline__ unsigned short f2bf(float f) {
    unsigned u = __float_as_uint(f);
    u += 0x7fffu + ((u >> 16) & 1u);   // RNE
    return (unsigned short)(u >> 16);
}
__device__ __forceinline__ float bf2f(unsigned short h) {
    return __uint_as_float((unsigned)h << 16);
}

// ---------------- weight pre-conversion ----------------

__global__ void convw1_kernel(const float* __restrict__ W, unsigned short* __restrict__ Wb,
                              int n4) {
    int i = blockIdx.x * blockDim.x + threadIdx.x;
    if (i < n4) {
        float4 v = ((const float4*)W)[i];
        ushort4 p;
        p.x = f2bf(v.x); p.y = f2bf(v.y); p.z = f2bf(v.z); p.w = f2bf(v.w);
        ((ushort4*)Wb)[i] = p;
    }
}

// pack Wmu (rows 0-63) + Wlg (rows 64-127) into [128][128], split hi/lo bf16
__global__ void convw2_kernel(const float* __restrict__ Wmu, const float* __restrict__ Wlg,
                              unsigned short* __restrict__ Wh, unsigned short* __restrict__ Wl) {
    int i = blockIdx.x * blockDim.x + threadIdx.x;  // 0..16383
    if (i < 128 * 128) {
        int r = i >> 7, c = i & 127;
        float f = (r < 64) ? Wmu[r * 128 + c] : Wlg[(r - 64) * 128 + c];
        unsigned short h = f2bf(f);
        Wh[i] = h;
        Wl[i] = f2bf(f - bf2f(h));
    }
}

// ---------------- degree / normalization ----------------

__global__ void count_kernel(const int* __restrict__ dst, int* __restrict__ cnt, int E) {
    int i = blockIdx.x * blockDim.x + threadIdx.x;
    if (i < E) atomicAdd(&cnt[dst[i]], 1);
}

__global__ void dinv_kernel(const int* __restrict__ cnt, float* __restrict__ dinv, int n) {
    int i = blockIdx.x * blockDim.x + threadIdx.x;
    if (i < n) dinv[i] = rsqrtf((float)(cnt[i] + 1));  // deg = in-degree + self-loop
}

// ---------------- exclusive scan (3 kernels, 1024 elems/block) ----------------

__global__ void scan1_kernel(const int* __restrict__ cnt, int* __restrict__ offs,
                             int* __restrict__ bsum, int n) {
    __shared__ int sdata[256];
    int t = threadIdx.x;
    int base = blockIdx.x * 1024 + t * 4;
    int4 c = make_int4(0, 0, 0, 0);
    if (base + 3 < n) {
        c = *(const int4*)(cnt + base);
    } else {
        if (base + 0 < n) c.x = cnt[base + 0];
        if (base + 1 < n) c.y = cnt[base + 1];
        if (base + 2 < n) c.z = cnt[base + 2];
        if (base + 3 < n) c.w = cnt[base + 3];
    }
    int s0 = c.x + c.y + c.z + c.w;
    sdata[t] = s0;
    __syncthreads();
    for (int off = 1; off < 256; off <<= 1) {
        int v = (t >= off) ? sdata[t - off] : 0;
        __syncthreads();
        sdata[t] += v;
        __syncthreads();
    }
    int excl = sdata[t] - s0;
    if (t == 255) bsum[blockIdx.x] = sdata[255];
    if (base + 0 < n) offs[base + 0] = excl;
    if (base + 1 < n) offs[base + 1] = excl + c.x;
    if (base + 2 < n) offs[base + 2] = excl + c.x + c.y;
    if (base + 3 < n) offs[base + 3] = excl + c.x + c.y + c.z;
}

__global__ void scan2_kernel(int* __restrict__ bsum, int nb) {
    __shared__ int sdata[256];
    int t = threadIdx.x;
    int v = (t < nb) ? bsum[t] : 0;
    sdata[t] = v;
    __syncthreads();
    for (int off = 1; off < 256; off <<= 1) {
        int u = (t >= off) ? sdata[t - off] : 0;
        __syncthreads();
        sdata[t] += u;
        __syncthreads();
    }
    if (t < nb) bsum[t] = sdata[t] - v;  // exclusive
}

__global__ void scan3_kernel(int* __restrict__ offs, const int* __restrict__ bsum,
                             int n, int E) {
    int i = blockIdx.x * blockDim.x + threadIdx.x;
    if (i < n) offs[i] += bsum[i >> 10];
    if (i == 0) offs[n] = E;
}

// ---------------- CSR fill (counting sort by dst) ----------------

__global__ void fill_kernel(const int* __restrict__ src, const int* __restrict__ dst,
                            const float* __restrict__ dinv, const int* __restrict__ offs,
                            int* __restrict__ cursor, int2* __restrict__ esort, int E) {
    int i = blockIdx.x * blockDim.x + threadIdx.x;
    if (i < E) {
        int s = src[i];
        int d = dst[i];
        int pos = offs[d] + atomicAdd(&cursor[d], 1);
        float w = dinv[s] * dinv[d];
        esort[pos] = make_int2(s, __float_as_int(w));
    }
}

// ---------------- SpMM gather: out[i] = dinv[i]^2*h[i] + sum_e norm_e * h[src_e] ---

__global__ void spmm_kernel(const float* __restrict__ hin, const int* __restrict__ offs,
                            const int2* __restrict__ esort, const float* __restrict__ dinv,
                            const float* __restrict__ bias, float* __restrict__ hout,
                            int n, int relu) {
    int gid = blockIdx.x * blockDim.x + threadIdx.x;
    int node = gid >> 6;            // one 64-lane wave per node
    int lane = threadIdx.x & 63;    // lane handles channels 2*lane, 2*lane+1
    if (node >= n) return;
    const float2* h2 = (const float2*)hin;
    float di = dinv[node];
    float2 hv = h2[(size_t)node * 64 + lane];
    float ax = di * di * hv.x;
    float ay = di * di * hv.y;
    int p = offs[node];
    int end = offs[node + 1];
    for (; p + 4 <= end; p += 4) {
        int2 e0 = esort[p + 0];
        int2 e1 = esort[p + 1];
        int2 e2 = esort[p + 2];
        int2 e3 = esort[p + 3];
        float2 v0 = h2[(size_t)e0.x * 64 + lane];
        float2 v1 = h2[(size_t)e1.x * 64 + lane];
        float2 v2 = h2[(size_t)e2.x * 64 + lane];
        float2 v3 = h2[(size_t)e3.x * 64 + lane];
        float w0 = __int_as_float(e0.y), w1 = __int_as_float(e1.y);
        float w2 = __int_as_float(e2.y), w3 = __int_as_float(e3.y);
        ax = fmaf(w0, v0.x, ax); ay = fmaf(w0, v0.y, ay);
        ax = fmaf(w1, v1.x, ax); ay = fmaf(w1, v1.y, ay);
        ax = fmaf(w2, v2.x, ax); ay = fmaf(w2, v2.y, ay);
        ax = fmaf(w3, v3.x, ax); ay = fmaf(w3, v3.y, ay);
    }
    for (; p < end; ++p) {
        int2 e = esort[p];
        float2 v = h2[(size_t)e.x * 64 + lane];
        float w = __int_as_float(e.y);
        ax = fmaf(w, v.x, ax); ay = fmaf(w, v.y, ay);
    }
    if (bias) {
        float2 b = ((const float2*)bias)[lane];
        ax += b.x; ay += b.y;
    }
    if (relu) { ax = fmaxf(ax, 0.f); ay = fmaxf(ay, 0.f); }
    float2 o; o.x = ax; o.y = ay;
    ((float2*)hout)[(size_t)node * 64 + lane] = o;
}

// ---------------- GEMM1: h[M,128] = X[M,512] @ W1b[128,512]^T  (bf16 MFMA) -------
// W-half in LDS (64 out-cols, 64KB, XOR-swizzled). 512 blocks x 8 waves; parity
// = column half. After prologue barrier, waves stream 16-row strips of X with
// depth-2 prefetch. Zero barriers / zero global B traffic in steady state.

__global__ __launch_bounds__(512) void gemm1_kernel(
    const float* __restrict__ X, const unsigned short* __restrict__ Wb,
    float* __restrict__ out, int M, int nstrips) {
    __shared__ __align__(16) unsigned short Bs[64 * 512];  // 64KB
    int tid = threadIdx.x;
    int p = blockIdx.x & 1;

    // stage 64 rows x 512 k of bf16 W, swizzled
    const short8* wsrc = (const short8*)(Wb + (size_t)p * 64 * FIN);
    #pragma unroll
    for (int j = 0; j < 8; ++j) {
        int f = tid + j * 512;              // 16B chunk id, 0..4095
        int row = f >> 6;                   // 64 chunks per row
        unsigned addr = ((unsigned)f * 16u) ^ ((unsigned)(row & 7) << 4);
        *(short8*)((char*)Bs + addr) = wsrc[f];
    }
    __syncthreads();

    int lane = tid & 63, wid = tid >> 6;
    int fr = lane & 15, fq = lane >> 4;
    int g = (blockIdx.x >> 1) * 8 + wid;    // 0..2047 per parity

    for (int s = g; s < nstrips; s += 2048) {
        int row0 = s * 16;
        int arow = row0 + fr; if (arow > M - 1) arow = M - 1;
        const float* ap = X + (size_t)arow * FIN + fq * 8;
        f32x4 acc0 = {}, acc1 = {}, acc2 = {}, acc3 = {};

        float4 p0a = *(const float4*)(ap + 0);
        float4 p0b = *(const float4*)(ap + 4);
        float4 p1a = *(const float4*)(ap + 32);
        float4 p1b = *(const float4*)(ap + 36);

        #pragma unroll
        for (int kk = 0; kk < 8; ++kk) {
            int k0 = kk * 64;
            // sub-iter A (uses p0, prefetch k0+64)
            {
                float4 c0 = p0a, c1 = p0b;
                if (kk < 7) {
                    p0a = *(const float4*)(ap + k0 + 64);
                    p0b = *(const float4*)(ap + k0 + 68);
                }
                short8 af;
                af[0] = (short)f2bf(c0.x); af[1] = (short)f2bf(c0.y);
                af[2] = (short)f2bf(c0.z); af[3] = (short)f2bf(c0.w);
                af[4] = (short)f2bf(c1.x); af[5] = (short)f2bf(c1.y);
                af[6] = (short)f2bf(c1.z); af[7] = (short)f2bf(c1.w);
                int cb = k0 * 2 + fq * 16;
                {
                    int lr = fr;
                    short8 bf = *(const short8*)((const char*)Bs +
                        (((unsigned)(lr * 1024 + cb)) ^ ((unsigned)(lr & 7) << 4)));
                    acc0 = __builtin_amdgcn_mfma_f32_16x16x32_bf16(af, bf, acc0, 0, 0, 0);
                }
                {
                    int lr = 16 + fr;
                    short8 bf = *(const short8*)((const char*)Bs +
                        (((unsigned)(lr * 1024 + cb)) ^ ((unsigned)(lr & 7) << 4)));
                    acc1 = __builtin_amdgcn_mfma_f32_16x16x32_bf16(af, bf, acc1, 0, 0, 0);
                }
                {
                    int lr = 32 + fr;
                    short8 bf = *(const short8*)((const char*)Bs +
                        (((unsigned)(lr * 1024 + cb)) ^ ((unsigned)(lr & 7) << 4)));
                    acc2 = __builtin_amdgcn_mfma_f32_16x16x32_bf16(af, bf, acc2, 0, 0, 0);
                }
                {
                    int lr = 48 + fr;
                    short8 bf = *(const short8*)((const char*)Bs +
                        (((unsigned)(lr * 1024 + cb)) ^ ((unsigned)(lr & 7) << 4)));
                    acc3 = __builtin_amdgcn_mfma_f32_16x16x32_bf16(af, bf, acc3, 0, 0, 0);
                }
            }
            // sub-iter B (uses p1, k0+32, prefetch k0+96)
            {
                float4 c0 = p1a, c1 = p1b;
                if (kk < 7) {
                    p1a = *(const float4*)(ap + k0 + 96);
                    p1b = *(const float4*)(ap + k0 + 100);
                }
                short8 af;
                af[0] = (short)f2bf(c0.x); af[1] = (short)f2bf(c0.y);
                af[2] = (short)f2bf(c0.z); af[3] = (short)f2bf(c0.w);
                af[4] = (short)f2bf(c1.x); af[5] = (short)f2bf(c1.y);
                af[6] = (short)f2bf(c1.z); af[7] = (short)f2bf(c1.w);
                int cb = (k0 + 32) * 2 + fq * 16;
                {
                    int lr = fr;
                    short8 bf = *(const short8*)((const char*)Bs +
                        (((unsigned)(lr * 1024 + cb)) ^ ((unsigned)(lr & 7) << 4)));
                    acc0 = __builtin_amdgcn_mfma_f32_16x16x32_bf16(af, bf, acc0, 0, 0, 0);
                }
                {
                    int lr = 16 + fr;
                    short8 bf = *(const short8*)((const char*)Bs +
                        (((unsigned)(lr * 1024 + cb)) ^ ((unsigned)(lr & 7) << 4)));
                    acc1 = __builtin_amdgcn_mfma_f32_16x16x32_bf16(af, bf, acc1, 0, 0, 0);
                }
                {
                    int lr = 32 + fr;
                    short8 bf = *(const short8*)((const char*)Bs +
                        (((unsigned)(lr * 1024 + cb)) ^ ((unsigned)(lr & 7) << 4)));
                    acc2 = __builtin_amdgcn_mfma_f32_16x16x32_bf16(af, bf, acc2, 0, 0, 0);
                }
                {
                    int lr = 48 + fr;
                    short8 bf = *(const short8*)((const char*)Bs +
                        (((unsigned)(lr * 1024 + cb)) ^ ((unsigned)(lr & 7) << 4)));
                    acc3 = __builtin_amdgcn_mfma_f32_16x16x32_bf16(af, bf, acc3, 0, 0, 0);
                }
            }
        }

        // store: col = p*64 + c*16 + fr, row = row0 + fq*4 + j
        int colbase = p * 64;
        #pragma unroll
        for (int j = 0; j < 4; ++j) {
            int row = row0 + fq * 4 + j;
            if (row < M) {
                float* op = out + (size_t)row * FH + colbase + fr;
                op[0]  = acc0[j];
                op[16] = acc1[j];
                op[32] = acc2[j];
                op[48] = acc3[j];
            }
        }
    }
}

// ---------------- GEMM2: mu/logstd[M,64] = ah2[M,128] @ W^T + b  (bf16x3) --------
// Whole W2 (hi+lo bf16, 64KB) in LDS. 512 blocks x 8 waves: every wave <=1 strip.

__global__ __launch_bounds__(512) void gemm2_kernel(
    const float* __restrict__ X,
    const unsigned short* __restrict__ Wh, const unsigned short* __restrict__ Wl,
    float* __restrict__ outA, float* __restrict__ outB,
    const float* __restrict__ biasA, const float* __restrict__ biasB,
    int M, int nstrips) {
    __shared__ __align__(16) unsigned short WhS[128 * 128];  // 32KB
    __shared__ __align__(16) unsigned short WlS[128 * 128];  // 32KB
    int tid = threadIdx.x;

    #pragma unroll
    for (int j = 0; j < 4; ++j) {
        int f = tid + j * 512;              // 16B chunk id, 0..2047
        int row = f >> 4;                   // 16 chunks per row
        unsigned addr = ((unsigned)f * 16u) ^ ((unsigned)(row & 7) << 4);
        *(short8*)((char*)WhS + addr) = ((const short8*)Wh)[f];
        *(short8*)((char*)WlS + addr) = ((const short8*)Wl)[f];
    }
    __syncthreads();

    int lane = tid & 63, wid = tid >> 6;
    int fr = lane & 15, fq = lane >> 4;
    int s = blockIdx.x * 8 + wid;
    if (s >= nstrips) return;
    int row0 = s * 16;
    int arow = row0 + fr; if (arow > M - 1) arow = M - 1;
    const float* ap = X + (size_t)arow * FH + fq * 8;

    float4 a0 = *(const float4*)(ap + 0);
    float4 a1 = *(const float4*)(ap + 4);
    float4 a2 = *(const float4*)(ap + 32);
    float4 a3 = *(const float4*)(ap + 36);
    float4 a4 = *(const float4*)(ap + 64);
    float4 a5 = *(const float4*)(ap + 68);
    float4 a6 = *(const float4*)(ap + 96);
    float4 a7 = *(const float4*)(ap + 100);

    f32x4 acc[8] = {};

    auto proc = [&](int k0, float4 c0, float4 c1) {
        float a[8] = {c0.x, c0.y, c0.z, c0.w, c1.x, c1.y, c1.z, c1.w};
        short8 ah, al;
        #pragma unroll
        for (int i = 0; i < 8; ++i) {
            unsigned short h = f2bf(a[i]);
            ah[i] = (short)h;
            al[i] = (short)f2bf(a[i] - bf2f(h));
        }
        int cb = k0 * 2 + fq * 16;
        #pragma unroll
        for (int c = 0; c < 8; ++c) {
            int lr = c * 16 + fr;
            unsigned addr = ((unsigned)(lr * 256 + cb)) ^ ((unsigned)(lr & 7) << 4);
            short8 bh = *(const short8*)((const char*)WhS + addr);
            short8 bl = *(const short8*)((const char*)WlS + addr);
            acc[c] = __builtin_amdgcn_mfma_f32_16x16x32_bf16(ah, bh, acc[c], 0, 0, 0);
            acc[c] = __builtin_amdgcn_mfma_f32_16x16x32_bf16(al, bh, acc[c], 0, 0, 0);
            acc[c] = __builtin_amdgcn_mfma_f32_16x16x32_bf16(ah, bl, acc[c], 0, 0, 0);
        }
    };
    proc(0, a0, a1);
    proc(32, a2, a3);
    proc(64, a4, a5);
    proc(96, a6, a7);

    #pragma unroll
    for (int c = 0; c < 8; ++c) {
        float* outp = (c < 4) ? outA : outB;
        const float* bp = (c < 4) ? biasA : biasB;
        int col = (c & 3) * 16 + fr;
        float bv = bp[col];
        #pragma unroll
        for (int j = 0; j < 4; ++j) {
            int row = row0 + fq * 4 + j;
            if (row < M) outp[(size_t)row * FO + col] = acc[c][j] + bv;
        }
    }
}

// ---------------- launch ----------------

extern "C" void kernel_launch(void* const* d_in, const int* in_sizes, int n_in,
                              void* d_out, int out_size, void* d_ws, size_t ws_size,
                              hipStream_t stream) {
    const float* x   = (const float*)d_in[0];
    const int*   ei  = (const int*)d_in[1];
    const float* W1  = (const float*)d_in[2];
    const float* b1  = (const float*)d_in[3];
    const float* Wmu = (const float*)d_in[4];
    const float* bmu = (const float*)d_in[5];
    const float* Wlg = (const float*)d_in[6];
    const float* blg = (const float*)d_in[7];

    const int n = in_sizes[0] / FIN;   // 50000
    const int E = in_sizes[1] / 2;     // 800000
    const int* src = ei;
    const int* dst = ei + E;
    const int nstrips = (n + 15) / 16; // 3125

    char* ws = (char*)d_ws;
    size_t off = 0;
    auto alloc = [&](size_t bytes) -> void* {
        void* p = ws + off;
        off = (off + bytes + 255) & ~((size_t)255);
        return p;
    };
    int*   cnt    = (int*)  alloc((size_t)n * 4);
    int*   offs   = (int*)  alloc((size_t)(n + 1) * 4);
    int*   cursor = (int*)  alloc((size_t)n * 4);
    int*   bsum   = (int*)  alloc(1024);
    float* dinv   = (float*)alloc((size_t)n * 4);
    int2*  esort  = (int2*) alloc((size_t)E * 8);
    float* h      = (float*)alloc((size_t)n * FH * 4);
    float* h1     = (float*)alloc((size_t)n * FH * 4);
    unsigned short* W1b = (unsigned short*)alloc((size_t)FH * FIN * 2);
    unsigned short* W2h = (unsigned short*)alloc((size_t)FH * FH * 2);
    unsigned short* W2l = (unsigned short*)alloc((size_t)FH * FH * 2);

    hipMemsetAsync(cnt, 0, (size_t)n * 4, stream);
    hipMemsetAsync(cursor, 0, (size_t)n * 4, stream);

    // weight conversions (independent of graph work)
    convw1_kernel<<<(FH * FIN / 4 + 255) / 256, 256, 0, stream>>>(W1, W1b, FH * FIN / 4);
    convw2_kernel<<<(FH * FH + 255) / 256, 256, 0, stream>>>(Wmu, Wlg, W2h, W2l);

    count_kernel<<<(E + 255) / 256, 256, 0, stream>>>(dst, cnt, E);
    dinv_kernel<<<(n + 255) / 256, 256, 0, stream>>>(cnt, dinv, n);

    int nb = (n + 1023) / 1024;  // 49
    scan1_kernel<<<nb, 256, 0, stream>>>(cnt, offs, bsum, n);
    scan2_kernel<<<1, 256, 0, stream>>>(bsum, nb);
    scan3_kernel<<<(n + 255) / 256, 256, 0, stream>>>(offs, bsum, n, E);

    fill_kernel<<<(E + 255) / 256, 256, 0, stream>>>(src, dst, dinv, offs, cursor, esort, E);

    // layer 1: h = x @ W1^T   (bf16 MFMA, W-half in LDS, persistent waves)
    gemm1_kernel<<<512, 512, 0, stream>>>(x, W1b, h, n, nstrips);
    // h1 = relu(A_norm @ h + b1)
    spmm_kernel<<<(n + 3) / 4, 256, 0, stream>>>(h, offs, esort, dinv, b1, h1, n, 1);
    // ah2 = A_norm @ h1 (reuse h buffer)
    spmm_kernel<<<(n + 3) / 4, 256, 0, stream>>>(h1, offs, esort, dinv, nullptr, h, n, 0);
    // mu / logstd = ah2 @ W^T + b   (bf16x3 MFMA, whole W2 in LDS)
    float* outmu = (float*)d_out;
    float* outlg = outmu + (size_t)n * FO;
    gemm2_kernel<<<512, 512, 0, stream>>>(h, W2h, W2l, outmu, outlg, bmu, blg, n, nstrips);
}

// Round 5
// 217.725 us; speedup vs baseline: 1.5453x; 1.3902x over previous
//
#include <hip/hip_runtime.h>

constexpr int FIN = 512;
constexpr int FH  = 128;
constexpr int FO  = 64;

typedef short short8 __attribute__((ext_vector_type(8)));
typedef float f32x4 __attribute__((ext_vector_type(4)));

__device__ __forceinline__ unsigned short f2bf(float f) {
    unsigned u = __float_as_uint(f);
    u += 0x7fffu + ((u >> 16) & 1u);   // RNE
    return (unsigned short)(u >> 16);
}
__device__ __forceinline__ float bf2f(unsigned short h) {
    return __uint_as_float((unsigned)h << 16);
}

// ---------------- weight pre-conversion ----------------

__global__ void convw1_kernel(const float* __restrict__ W, unsigned short* __restrict__ Wb,
                              int n4) {
    int i = blockIdx.x * blockDim.x + threadIdx.x;
    if (i < n4) {
        float4 v = ((const float4*)W)[i];
        ushort4 p;
        p.x = f2bf(v.x); p.y = f2bf(v.y); p.z = f2bf(v.z); p.w = f2bf(v.w);
        ((ushort4*)Wb)[i] = p;
    }
}

// pack Wmu (rows 0-63) + Wlg (rows 64-127) into [128][128], split hi/lo bf16
__global__ void convw2_kernel(const float* __restrict__ Wmu, const float* __restrict__ Wlg,
                              unsigned short* __restrict__ Wh, unsigned short* __restrict__ Wl) {
    int i = blockIdx.x * blockDim.x + threadIdx.x;  // 0..16383
    if (i < 128 * 128) {
        int r = i >> 7, c = i & 127;
        float f = (r < 64) ? Wmu[r * 128 + c] : Wlg[(r - 64) * 128 + c];
        unsigned short h = f2bf(f);
        Wh[i] = h;
        Wl[i] = f2bf(f - bf2f(h));
    }
}

// ---------------- degree / normalization ----------------

__global__ void count_kernel(const int* __restrict__ dst, int* __restrict__ cnt, int E) {
    int i = blockIdx.x * blockDim.x + threadIdx.x;
    if (i < E) atomicAdd(&cnt[dst[i]], 1);
}

__global__ void dinv_kernel(const int* __restrict__ cnt, float* __restrict__ dinv, int n) {
    int i = blockIdx.x * blockDim.x + threadIdx.x;
    if (i < n) dinv[i] = rsqrtf((float)(cnt[i] + 1));  // deg = in-degree + self-loop
}

// ---------------- exclusive scan (3 kernels, 1024 elems/block) ----------------

__global__ void scan1_kernel(const int* __restrict__ cnt, int* __restrict__ offs,
                             int* __restrict__ bsum, int n) {
    __shared__ int sdata[256];
    int t = threadIdx.x;
    int base = blockIdx.x * 1024 + t * 4;
    int4 c = make_int4(0, 0, 0, 0);
    if (base + 3 < n) {
        c = *(const int4*)(cnt + base);
    } else {
        if (base + 0 < n) c.x = cnt[base + 0];
        if (base + 1 < n) c.y = cnt[base + 1];
        if (base + 2 < n) c.z = cnt[base + 2];
        if (base + 3 < n) c.w = cnt[base + 3];
    }
    int s0 = c.x + c.y + c.z + c.w;
    sdata[t] = s0;
    __syncthreads();
    for (int off = 1; off < 256; off <<= 1) {
        int v = (t >= off) ? sdata[t - off] : 0;
        __syncthreads();
        sdata[t] += v;
        __syncthreads();
    }
    int excl = sdata[t] - s0;
    if (t == 255) bsum[blockIdx.x] = sdata[255];
    if (base + 0 < n) offs[base + 0] = excl;
    if (base + 1 < n) offs[base + 1] = excl + c.x;
    if (base + 2 < n) offs[base + 2] = excl + c.x + c.y;
    if (base + 3 < n) offs[base + 3] = excl + c.x + c.y + c.z;
}

__global__ void scan2_kernel(int* __restrict__ bsum, int nb) {
    __shared__ int sdata[256];
    int t = threadIdx.x;
    int v = (t < nb) ? bsum[t] : 0;
    sdata[t] = v;
    __syncthreads();
    for (int off = 1; off < 256; off <<= 1) {
        int u = (t >= off) ? sdata[t - off] : 0;
        __syncthreads();
        sdata[t] += u;
        __syncthreads();
    }
    if (t < nb) bsum[t] = sdata[t] - v;  // exclusive
}

__global__ void scan3_kernel(int* __restrict__ offs, const int* __restrict__ bsum,
                             int n, int E) {
    int i = blockIdx.x * blockDim.x + threadIdx.x;
    if (i < n) offs[i] += bsum[i >> 10];
    if (i == 0) offs[n] = E;
}

// ---------------- CSR fill (counting sort by dst) ----------------

__global__ void fill_kernel(const int* __restrict__ src, const int* __restrict__ dst,
                            const float* __restrict__ dinv, const int* __restrict__ offs,
                            int* __restrict__ cursor, int2* __restrict__ esort, int E) {
    int i = blockIdx.x * blockDim.x + threadIdx.x;
    if (i < E) {
        int s = src[i];
        int d = dst[i];
        int pos = offs[d] + atomicAdd(&cursor[d], 1);
        float w = dinv[s] * dinv[d];
        esort[pos] = make_int2(s, __float_as_int(w));
    }
}

// ---------------- SpMM gather (bf16 table): out[i] = dinv^2*h[i] + sum norm*h[src] --
// hin: bf16 [n][128] packed as uint pairs. obf=1: relu + bf16 out; obf=0: fp32 out.

__global__ void spmm_kernel(const unsigned int* __restrict__ hin, const int* __restrict__ offs,
                            const int2* __restrict__ esort, const float* __restrict__ dinv,
                            const float* __restrict__ bias, void* __restrict__ hout,
                            int n, int obf) {
    int gid = blockIdx.x * blockDim.x + threadIdx.x;
    int node = gid >> 6;            // one 64-lane wave per node
    int lane = threadIdx.x & 63;    // lane handles channels 2*lane, 2*lane+1
    if (node >= n) return;
    float di = dinv[node];
    unsigned hv = hin[(size_t)node * 64 + lane];
    float ax = di * di * __uint_as_float(hv << 16);
    float ay = di * di * __uint_as_float(hv & 0xffff0000u);
    int p = offs[node];
    int end = offs[node + 1];
    for (; p + 4 <= end; p += 4) {
        int2 e0 = esort[p + 0];
        int2 e1 = esort[p + 1];
        int2 e2 = esort[p + 2];
        int2 e3 = esort[p + 3];
        unsigned v0 = hin[(size_t)e0.x * 64 + lane];
        unsigned v1 = hin[(size_t)e1.x * 64 + lane];
        unsigned v2 = hin[(size_t)e2.x * 64 + lane];
        unsigned v3 = hin[(size_t)e3.x * 64 + lane];
        float w0 = __int_as_float(e0.y), w1 = __int_as_float(e1.y);
        float w2 = __int_as_float(e2.y), w3 = __int_as_float(e3.y);
        ax = fmaf(w0, __uint_as_float(v0 << 16), ax);
        ay = fmaf(w0, __uint_as_float(v0 & 0xffff0000u), ay);
        ax = fmaf(w1, __uint_as_float(v1 << 16), ax);
        ay = fmaf(w1, __uint_as_float(v1 & 0xffff0000u), ay);
        ax = fmaf(w2, __uint_as_float(v2 << 16), ax);
        ay = fmaf(w2, __uint_as_float(v2 & 0xffff0000u), ay);
        ax = fmaf(w3, __uint_as_float(v3 << 16), ax);
        ay = fmaf(w3, __uint_as_float(v3 & 0xffff0000u), ay);
    }
    for (; p < end; ++p) {
        int2 e = esort[p];
        unsigned v = hin[(size_t)e.x * 64 + lane];
        float w = __int_as_float(e.y);
        ax = fmaf(w, __uint_as_float(v << 16), ax);
        ay = fmaf(w, __uint_as_float(v & 0xffff0000u), ay);
    }
    if (bias) {
        float2 b = ((const float2*)bias)[lane];
        ax += b.x; ay += b.y;
    }
    if (obf) {
        ax = fmaxf(ax, 0.f); ay = fmaxf(ay, 0.f);
        unsigned o = (unsigned)f2bf(ax) | ((unsigned)f2bf(ay) << 16);
        ((unsigned*)hout)[(size_t)node * 64 + lane] = o;
    } else {
        float2 o; o.x = ax; o.y = ay;
        ((float2*)hout)[(size_t)node * 64 + lane] = o;
    }
}

// ---------------- GEMM1: h[M,128](bf16) = X[M,512] @ W1b[128,512]^T ----------------
// Cooperative 64x128 tile, BK=64, double-buffered LDS (48KB -> 3 blocks/CU),
// async-split staging: issue next tile's global loads before compute (T14).
// 4 waves; wave w owns rows [w*16, w*16+16) x all 128 cols (acc = 8 f32x4).

__global__ __launch_bounds__(256, 3) void gemm1_kernel(
    const float* __restrict__ X, const unsigned short* __restrict__ Wb,
    unsigned short* __restrict__ out, int M) {
    __shared__ __align__(16) unsigned short As[2][64 * 64];    // 8KB each
    __shared__ __align__(16) unsigned short Bs[2][128 * 64];   // 16KB each

    int tid = threadIdx.x;
    int lane = tid & 63, wid = tid >> 6;
    int fr = lane & 15, fq = lane >> 4;
    int row0 = blockIdx.x * 64;

    // staging decomposition (per thread, 4 chunks each for A and B)
    int a_r = tid >> 4, a_kq = tid & 15;       // A: row 0..15 (+16j), float4 idx
    int b_r = tid >> 3, b_c = tid & 7;         // B: row 0..31 (+32j), short8 idx

    f32x4 acc[8] = {};
    float4 a_reg[4];
    short8 b_reg[4];

    auto issue = [&](int k0) {
        #pragma unroll
        for (int j = 0; j < 4; ++j) {
            int ar = a_r + 16 * j;
            int grow = row0 + ar; if (grow >= M) grow = M - 1;
            a_reg[j] = *(const float4*)(X + (size_t)grow * FIN + k0 + a_kq * 4);
            int br = b_r + 32 * j;
            b_reg[j] = *(const short8*)(Wb + (size_t)br * FIN + k0 + b_c * 8);
        }
    };
    auto commit = [&](int buf) {
        #pragma unroll
        for (int j = 0; j < 4; ++j) {
            int ar = a_r + 16 * j;
            ushort4 p;
            p.x = f2bf(a_reg[j].x); p.y = f2bf(a_reg[j].y);
            p.z = f2bf(a_reg[j].z); p.w = f2bf(a_reg[j].w);
            *(ushort4*)((char*)As[buf] + ar * 128 + ((a_kq * 8) ^ ((ar & 7) << 4))) = p;
            int br = b_r + 32 * j;
            *(short8*)((char*)Bs[buf] + br * 128 + ((b_c * 16) ^ ((br & 7) << 4))) = b_reg[j];
        }
    };
    auto compute = [&](int buf) {
        #pragma unroll
        for (int s = 0; s < 2; ++s) {
            int r = wid * 16 + fr;
            short8 af = *(const short8*)((const char*)As[buf] + r * 128 +
                                         ((s * 64 + fq * 16) ^ ((r & 7) << 4)));
            #pragma unroll
            for (int c = 0; c < 8; ++c) {
                int br = c * 16 + fr;
                short8 bfr = *(const short8*)((const char*)Bs[buf] + br * 128 +
                                              ((s * 64 + fq * 16) ^ ((br & 7) << 4)));
                acc[c] = __builtin_amdgcn_mfma_f32_16x16x32_bf16(af, bfr, acc[c], 0, 0, 0);
            }
        }
    };

    issue(0);
    commit(0);
    __syncthreads();
    for (int kk = 0; kk < 7; ++kk) {
        issue((kk + 1) * 64);
        compute(kk & 1);
        __syncthreads();
        commit((kk + 1) & 1);
        __syncthreads();
    }
    compute(1);

    // store bf16: col = c*16+fr, row = row0 + wid*16 + fq*4 + j
    #pragma unroll
    for (int c = 0; c < 8; ++c) {
        #pragma unroll
        for (int j = 0; j < 4; ++j) {
            int row = row0 + wid * 16 + fq * 4 + j;
            if (row < M) out[(size_t)row * FH + c * 16 + fr] = f2bf(acc[c][j]);
        }
    }
}

// ---------------- GEMM2: mu/logstd[M,64] = ah2[M,128] @ W^T + b  (bf16x3) --------
// Whole W2 (hi+lo bf16, 64KB) in LDS. 512 blocks x 8 waves: every wave <=1 strip.

__global__ __launch_bounds__(512) void gemm2_kernel(
    const float* __restrict__ X,
    const unsigned short* __restrict__ Wh, const unsigned short* __restrict__ Wl,
    float* __restrict__ outA, float* __restrict__ outB,
    const float* __restrict__ biasA, const float* __restrict__ biasB,
    int M, int nstrips) {
    __shared__ __align__(16) unsigned short WhS[128 * 128];  // 32KB
    __shared__ __align__(16) unsigned short WlS[128 * 128];  // 32KB
    int tid = threadIdx.x;

    #pragma unroll
    for (int j = 0; j < 4; ++j) {
        int f = tid + j * 512;              // 16B chunk id, 0..2047
        int row = f >> 4;                   // 16 chunks per row
        unsigned addr = ((unsigned)f * 16u) ^ ((unsigned)(row & 7) << 4);
        *(short8*)((char*)WhS + addr) = ((const short8*)Wh)[f];
        *(short8*)((char*)WlS + addr) = ((const short8*)Wl)[f];
    }
    __syncthreads();

    int lane = tid & 63, wid = tid >> 6;
    int fr = lane & 15, fq = lane >> 4;
    int s = blockIdx.x * 8 + wid;
    if (s >= nstrips) return;
    int row0 = s * 16;
    int arow = row0 + fr; if (arow > M - 1) arow = M - 1;
    const float* ap = X + (size_t)arow * FH + fq * 8;

    float4 a0 = *(const float4*)(ap + 0);
    float4 a1 = *(const float4*)(ap + 4);
    float4 a2 = *(const float4*)(ap + 32);
    float4 a3 = *(const float4*)(ap + 36);
    float4 a4 = *(const float4*)(ap + 64);
    float4 a5 = *(const float4*)(ap + 68);
    float4 a6 = *(const float4*)(ap + 96);
    float4 a7 = *(const float4*)(ap + 100);

    f32x4 acc[8] = {};

    auto proc = [&](int k0, float4 c0, float4 c1) {
        float a[8] = {c0.x, c0.y, c0.z, c0.w, c1.x, c1.y, c1.z, c1.w};
        short8 ah, al;
        #pragma unroll
        for (int i = 0; i < 8; ++i) {
            unsigned short h = f2bf(a[i]);
            ah[i] = (short)h;
            al[i] = (short)f2bf(a[i] - bf2f(h));
        }
        int cb = k0 * 2 + fq * 16;
        #pragma unroll
        for (int c = 0; c < 8; ++c) {
            int lr = c * 16 + fr;
            unsigned addr = ((unsigned)(lr * 256 + cb)) ^ ((unsigned)(lr & 7) << 4);
            short8 bh = *(const short8*)((const char*)WhS + addr);
            short8 bl = *(const short8*)((const char*)WlS + addr);
            acc[c] = __builtin_amdgcn_mfma_f32_16x16x32_bf16(ah, bh, acc[c], 0, 0, 0);
            acc[c] = __builtin_amdgcn_mfma_f32_16x16x32_bf16(al, bh, acc[c], 0, 0, 0);
            acc[c] = __builtin_amdgcn_mfma_f32_16x16x32_bf16(ah, bl, acc[c], 0, 0, 0);
        }
    };
    proc(0, a0, a1);
    proc(32, a2, a3);
    proc(64, a4, a5);
    proc(96, a6, a7);

    #pragma unroll
    for (int c = 0; c < 8; ++c) {
        float* outp = (c < 4) ? outA : outB;
        const float* bp = (c < 4) ? biasA : biasB;
        int col = (c & 3) * 16 + fr;
        float bv = bp[col];
        #pragma unroll
        for (int j = 0; j < 4; ++j) {
            int row = row0 + fq * 4 + j;
            if (row < M) outp[(size_t)row * FO + col] = acc[c][j] + bv;
        }
    }
}

// ---------------- launch ----------------

extern "C" void kernel_launch(void* const* d_in, const int* in_sizes, int n_in,
                              void* d_out, int out_size, void* d_ws, size_t ws_size,
                              hipStream_t stream) {
    const float* x   = (const float*)d_in[0];
    const int*   ei  = (const int*)d_in[1];
    const float* W1  = (const float*)d_in[2];
    const float* b1  = (const float*)d_in[3];
    const float* Wmu = (const float*)d_in[4];
    const float* bmu = (const float*)d_in[5];
    const float* Wlg = (const float*)d_in[6];
    const float* blg = (const float*)d_in[7];

    const int n = in_sizes[0] / FIN;   // 50000
    const int E = in_sizes[1] / 2;     // 800000
    const int* src = ei;
    const int* dst = ei + E;
    const int nstrips = (n + 15) / 16; // 3125

    char* ws = (char*)d_ws;
    size_t off = 0;
    auto alloc = [&](size_t bytes) -> void* {
        void* p = ws + off;
        off = (off + bytes + 255) & ~((size_t)255);
        return p;
    };
    int*   cnt    = (int*)  alloc((size_t)n * 4);
    int*   offs   = (int*)  alloc((size_t)(n + 1) * 4);
    int*   cursor = (int*)  alloc((size_t)n * 4);
    int*   bsum   = (int*)  alloc(1024);
    float* dinv   = (float*)alloc((size_t)n * 4);
    int2*  esort  = (int2*) alloc((size_t)E * 8);
    unsigned short* hbf  = (unsigned short*)alloc((size_t)n * FH * 2);  // bf16 h
    unsigned short* h1bf = (unsigned short*)alloc((size_t)n * FH * 2);  // bf16 h1
    float* ah2    = (float*)alloc((size_t)n * FH * 4);                   // fp32
    unsigned short* W1b = (unsigned short*)alloc((size_t)FH * FIN * 2);
    unsigned short* W2h = (unsigned short*)alloc((size_t)FH * FH * 2);
    unsigned short* W2l = (unsigned short*)alloc((size_t)FH * FH * 2);

    hipMemsetAsync(cnt, 0, (size_t)n * 4, stream);
    hipMemsetAsync(cursor, 0, (size_t)n * 4, stream);

    // weight conversions (independent of graph work)
    convw1_kernel<<<(FH * FIN / 4 + 255) / 256, 256, 0, stream>>>(W1, W1b, FH * FIN / 4);
    convw2_kernel<<<(FH * FH + 255) / 256, 256, 0, stream>>>(Wmu, Wlg, W2h, W2l);

    count_kernel<<<(E + 255) / 256, 256, 0, stream>>>(dst, cnt, E);
    dinv_kernel<<<(n + 255) / 256, 256, 0, stream>>>(cnt, dinv, n);

    int nb = (n + 1023) / 1024;  // 49
    scan1_kernel<<<nb, 256, 0, stream>>>(cnt, offs, bsum, n);
    scan2_kernel<<<1, 256, 0, stream>>>(bsum, nb);
    scan3_kernel<<<(n + 255) / 256, 256, 0, stream>>>(offs, bsum, n, E);

    fill_kernel<<<(E + 255) / 256, 256, 0, stream>>>(src, dst, dinv, offs, cursor, esort, E);

    // layer 1: h = x @ W1^T   (bf16 MFMA, cooperative dbuf tile, bf16 out)
    gemm1_kernel<<<(n + 63) / 64, 256, 0, stream>>>(x, W1b, hbf, n);
    // h1 = relu(A_norm @ h + b1)  (bf16 gather table, bf16 out)
    spmm_kernel<<<(n + 3) / 4, 256, 0, stream>>>(
        (const unsigned*)hbf, offs, esort, dinv, b1, h1bf, n, 1);
    // ah2 = A_norm @ h1  (bf16 gathers, fp32 out)
    spmm_kernel<<<(n + 3) / 4, 256, 0, stream>>>(
        (const unsigned*)h1bf, offs, esort, dinv, nullptr, ah2, n, 0);
    // mu / logstd = ah2 @ W^T + b   (bf16x3 MFMA, whole W2 in LDS)
    float* outmu = (float*)d_out;
    float* outlg = outmu + (size_t)n * FO;
    gemm2_kernel<<<512, 512, 0, stream>>>(ah2, W2h, W2l, outmu, outlg, bmu, blg, n, nstrips);
}

// Round 6
// 210.724 us; speedup vs baseline: 1.5966x; 1.0332x over previous
//
#include <hip/hip_runtime.h>

constexpr int FIN = 512;
constexpr int FH  = 128;
constexpr int FO  = 64;

typedef short short8 __attribute__((ext_vector_type(8)));
typedef float f32x4 __attribute__((ext_vector_type(4)));

__device__ __forceinline__ unsigned short f2bf(float f) {
    unsigned u = __float_as_uint(f);
    u += 0x7fffu + ((u >> 16) & 1u);   // RNE
    return (unsigned short)(u >> 16);
}
__device__ __forceinline__ float bf2f(unsigned short h) {
    return __uint_as_float((unsigned)h << 16);
}

// ---------------- weight pre-conversion ----------------

__global__ void convw1_kernel(const float* __restrict__ W, unsigned short* __restrict__ Wb,
                              int n4) {
    int i = blockIdx.x * blockDim.x + threadIdx.x;
    if (i < n4) {
        float4 v = ((const float4*)W)[i];
        ushort4 p;
        p.x = f2bf(v.x); p.y = f2bf(v.y); p.z = f2bf(v.z); p.w = f2bf(v.w);
        ((ushort4*)Wb)[i] = p;
    }
}

// pack Wmu (rows 0-63) + Wlg (rows 64-127) into [128][128], split hi/lo bf16
__global__ void convw2_kernel(const float* __restrict__ Wmu, const float* __restrict__ Wlg,
                              unsigned short* __restrict__ Wh, unsigned short* __restrict__ Wl) {
    int i = blockIdx.x * blockDim.x + threadIdx.x;  // 0..16383
    if (i < 128 * 128) {
        int r = i >> 7, c = i & 127;
        float f = (r < 64) ? Wmu[r * 128 + c] : Wlg[(r - 64) * 128 + c];
        unsigned short h = f2bf(f);
        Wh[i] = h;
        Wl[i] = f2bf(f - bf2f(h));
    }
}

// ---------------- degree / normalization ----------------

__global__ void count_kernel(const int* __restrict__ dst, int* __restrict__ cnt, int E) {
    int i = blockIdx.x * blockDim.x + threadIdx.x;
    if (i < E) atomicAdd(&cnt[dst[i]], 1);
}

__global__ void dinv_kernel(const int* __restrict__ cnt, float* __restrict__ dinv, int n) {
    int i = blockIdx.x * blockDim.x + threadIdx.x;
    if (i < n) dinv[i] = rsqrtf((float)(cnt[i] + 1));  // deg = in-degree + self-loop
}

// ---------------- exclusive scan (3 kernels, 1024 elems/block) ----------------

__global__ void scan1_kernel(const int* __restrict__ cnt, int* __restrict__ offs,
                             int* __restrict__ bsum, int n) {
    __shared__ int sdata[256];
    int t = threadIdx.x;
    int base = blockIdx.x * 1024 + t * 4;
    int4 c = make_int4(0, 0, 0, 0);
    if (base + 3 < n) {
        c = *(const int4*)(cnt + base);
    } else {
        if (base + 0 < n) c.x = cnt[base + 0];
        if (base + 1 < n) c.y = cnt[base + 1];
        if (base + 2 < n) c.z = cnt[base + 2];
        if (base + 3 < n) c.w = cnt[base + 3];
    }
    int s0 = c.x + c.y + c.z + c.w;
    sdata[t] = s0;
    __syncthreads();
    for (int off = 1; off < 256; off <<= 1) {
        int v = (t >= off) ? sdata[t - off] : 0;
        __syncthreads();
        sdata[t] += v;
        __syncthreads();
    }
    int excl = sdata[t] - s0;
    if (t == 255) bsum[blockIdx.x] = sdata[255];
    if (base + 0 < n) offs[base + 0] = excl;
    if (base + 1 < n) offs[base + 1] = excl + c.x;
    if (base + 2 < n) offs[base + 2] = excl + c.x + c.y;
    if (base + 3 < n) offs[base + 3] = excl + c.x + c.y + c.z;
}

__global__ void scan2_kernel(int* __restrict__ bsum, int nb) {
    __shared__ int sdata[256];
    int t = threadIdx.x;
    int v = (t < nb) ? bsum[t] : 0;
    sdata[t] = v;
    __syncthreads();
    for (int off = 1; off < 256; off <<= 1) {
        int u = (t >= off) ? sdata[t - off] : 0;
        __syncthreads();
        sdata[t] += u;
        __syncthreads();
    }
    if (t < nb) bsum[t] = sdata[t] - v;  // exclusive
}

__global__ void scan3_kernel(int* __restrict__ offs, const int* __restrict__ bsum,
                             int n, int E) {
    int i = blockIdx.x * blockDim.x + threadIdx.x;
    if (i < n) offs[i] += bsum[i >> 10];
    if (i == 0) offs[n] = E;
}

// ---------------- CSR fill (counting sort by dst) ----------------

__global__ void fill_kernel(const int* __restrict__ src, const int* __restrict__ dst,
                            const float* __restrict__ dinv, const int* __restrict__ offs,
                            int* __restrict__ cursor, int2* __restrict__ esort, int E) {
    int i = blockIdx.x * blockDim.x + threadIdx.x;
    if (i < E) {
        int s = src[i];
        int d = dst[i];
        int pos = offs[d] + atomicAdd(&cursor[d], 1);
        float w = dinv[s] * dinv[d];
        esort[pos] = make_int2(s, __float_as_int(w));
    }
}

// ---------------- SpMM gather (bf16 table): out[i] = dinv^2*h[i] + sum norm*h[src] --
// hin: bf16 [n][128] packed as uint pairs. Output bf16 (relu optional).

__global__ void spmm_kernel(const unsigned int* __restrict__ hin, const int* __restrict__ offs,
                            const int2* __restrict__ esort, const float* __restrict__ dinv,
                            const float* __restrict__ bias, unsigned int* __restrict__ hout,
                            int n, int relu) {
    int gid = blockIdx.x * blockDim.x + threadIdx.x;
    int node = gid >> 6;            // one 64-lane wave per node
    int lane = threadIdx.x & 63;    // lane handles channels 2*lane, 2*lane+1
    if (node >= n) return;
    float di = dinv[node];
    unsigned hv = hin[(size_t)node * 64 + lane];
    float ax = di * di * __uint_as_float(hv << 16);
    float ay = di * di * __uint_as_float(hv & 0xffff0000u);
    int p = offs[node];
    int end = offs[node + 1];
    for (; p + 4 <= end; p += 4) {
        int2 e0 = esort[p + 0];
        int2 e1 = esort[p + 1];
        int2 e2 = esort[p + 2];
        int2 e3 = esort[p + 3];
        unsigned v0 = hin[(size_t)e0.x * 64 + lane];
        unsigned v1 = hin[(size_t)e1.x * 64 + lane];
        unsigned v2 = hin[(size_t)e2.x * 64 + lane];
        unsigned v3 = hin[(size_t)e3.x * 64 + lane];
        float w0 = __int_as_float(e0.y), w1 = __int_as_float(e1.y);
        float w2 = __int_as_float(e2.y), w3 = __int_as_float(e3.y);
        ax = fmaf(w0, __uint_as_float(v0 << 16), ax);
        ay = fmaf(w0, __uint_as_float(v0 & 0xffff0000u), ay);
        ax = fmaf(w1, __uint_as_float(v1 << 16), ax);
        ay = fmaf(w1, __uint_as_float(v1 & 0xffff0000u), ay);
        ax = fmaf(w2, __uint_as_float(v2 << 16), ax);
        ay = fmaf(w2, __uint_as_float(v2 & 0xffff0000u), ay);
        ax = fmaf(w3, __uint_as_float(v3 << 16), ax);
        ay = fmaf(w3, __uint_as_float(v3 & 0xffff0000u), ay);
    }
    for (; p < end; ++p) {
        int2 e = esort[p];
        unsigned v = hin[(size_t)e.x * 64 + lane];
        float w = __int_as_float(e.y);
        ax = fmaf(w, __uint_as_float(v << 16), ax);
        ay = fmaf(w, __uint_as_float(v & 0xffff0000u), ay);
    }
    if (bias) {
        float2 b = ((const float2*)bias)[lane];
        ax += b.x; ay += b.y;
    }
    if (relu) { ax = fmaxf(ax, 0.f); ay = fmaxf(ay, 0.f); }
    unsigned o = (unsigned)f2bf(ax) | ((unsigned)f2bf(ay) << 16);
    hout[(size_t)node * 64 + lane] = o;
}

// ---------------- GEMM1: h[M,128](bf16) = X[M,512] @ W1b[128,512]^T ----------------
// Cooperative 64x128 tile, BK=64, double-buffered LDS (48KB -> 3 blocks/CU).
// ONE barrier per K-step: compute(buf[k]) || commit(regs->buf[k+1]); issue(k+2).
// Loads get ~2 compute phases of latency cover (T3 2-phase recipe, reg-staged).

__global__ __launch_bounds__(256, 3) void gemm1_kernel(
    const float* __restrict__ X, const unsigned short* __restrict__ Wb,
    unsigned short* __restrict__ out, int M) {
    __shared__ __align__(16) unsigned short As[2][64 * 64];    // 8KB each
    __shared__ __align__(16) unsigned short Bs[2][128 * 64];   // 16KB each

    int tid = threadIdx.x;
    int lane = tid & 63, wid = tid >> 6;
    int fr = lane & 15, fq = lane >> 4;
    int row0 = blockIdx.x * 64;

    // staging decomposition (per thread, 4 chunks each for A and B)
    int a_r = tid >> 4, a_kq = tid & 15;       // A: row 0..15 (+16j), float4 idx
    int b_r = tid >> 3, b_c = tid & 7;         // B: row 0..31 (+32j), short8 idx

    f32x4 acc[8] = {};
    float4 a_reg[4];
    short8 b_reg[4];

    auto issue = [&](int k0) {
        #pragma unroll
        for (int j = 0; j < 4; ++j) {
            int ar = a_r + 16 * j;
            int grow = row0 + ar; if (grow >= M) grow = M - 1;
            a_reg[j] = *(const float4*)(X + (size_t)grow * FIN + k0 + a_kq * 4);
            int br = b_r + 32 * j;
            b_reg[j] = *(const short8*)(Wb + (size_t)br * FIN + k0 + b_c * 8);
        }
    };
    auto commit = [&](int buf) {
        #pragma unroll
        for (int j = 0; j < 4; ++j) {
            int ar = a_r + 16 * j;
            ushort4 p;
            p.x = f2bf(a_reg[j].x); p.y = f2bf(a_reg[j].y);
            p.z = f2bf(a_reg[j].z); p.w = f2bf(a_reg[j].w);
            *(ushort4*)((char*)As[buf] + ar * 128 + ((a_kq * 8) ^ ((ar & 7) << 4))) = p;
            int br = b_r + 32 * j;
            *(short8*)((char*)Bs[buf] + br * 128 + ((b_c * 16) ^ ((br & 7) << 4))) = b_reg[j];
        }
    };
    auto compute = [&](int buf) {
        #pragma unroll
        for (int s = 0; s < 2; ++s) {
            int r = wid * 16 + fr;
            short8 af = *(const short8*)((const char*)As[buf] + r * 128 +
                                         ((s * 64 + fq * 16) ^ ((r & 7) << 4)));
            #pragma unroll
            for (int c = 0; c < 8; ++c) {
                int br = c * 16 + fr;
                short8 bfr = *(const short8*)((const char*)Bs[buf] + br * 128 +
                                              ((s * 64 + fq * 16) ^ ((br & 7) << 4)));
                acc[c] = __builtin_amdgcn_mfma_f32_16x16x32_bf16(af, bfr, acc[c], 0, 0, 0);
            }
        }
    };

    issue(0);
    commit(0);
    issue(64);
    __syncthreads();
    for (int kk = 0; kk < 8; ++kk) {
        compute(kk & 1);
        if (kk < 7) commit((kk + 1) & 1);   // waits loads(kk+1); writes other buffer
        if (kk < 6) issue((kk + 2) * 64);
        __syncthreads();
    }

    // store bf16: col = c*16+fr, row = row0 + wid*16 + fq*4 + j
    #pragma unroll
    for (int c = 0; c < 8; ++c) {
        #pragma unroll
        for (int j = 0; j < 4; ++j) {
            int row = row0 + wid * 16 + fq * 4 + j;
            if (row < M) out[(size_t)row * FH + c * 16 + fr] = f2bf(acc[c][j]);
        }
    }
}

// ---------------- GEMM2: mu/logstd[M,64] = ah2b[M,128](bf16) @ W^T + b ------------
// A is bf16 (no split); B split hi/lo -> 2 MFMA per fragment (~fp32 weight fidelity).
// Whole W2 (hi+lo bf16, 64KB) in LDS. 512 blocks x 8 waves: every wave <=1 strip.

__global__ __launch_bounds__(512) void gemm2_kernel(
    const unsigned short* __restrict__ Xb,
    const unsigned short* __restrict__ Wh, const unsigned short* __restrict__ Wl,
    float* __restrict__ outA, float* __restrict__ outB,
    const float* __restrict__ biasA, const float* __restrict__ biasB,
    int M, int nstrips) {
    __shared__ __align__(16) unsigned short WhS[128 * 128];  // 32KB
    __shared__ __align__(16) unsigned short WlS[128 * 128];  // 32KB
    int tid = threadIdx.x;

    #pragma unroll
    for (int j = 0; j < 4; ++j) {
        int f = tid + j * 512;              // 16B chunk id, 0..2047
        int row = f >> 4;                   // 16 chunks per row
        unsigned addr = ((unsigned)f * 16u) ^ ((unsigned)(row & 7) << 4);
        *(short8*)((char*)WhS + addr) = ((const short8*)Wh)[f];
        *(short8*)((char*)WlS + addr) = ((const short8*)Wl)[f];
    }
    __syncthreads();

    int lane = tid & 63, wid = tid >> 6;
    int fr = lane & 15, fq = lane >> 4;
    int s = blockIdx.x * 8 + wid;
    if (s >= nstrips) return;
    int row0 = s * 16;
    int arow = row0 + fr; if (arow > M - 1) arow = M - 1;
    const unsigned short* ap = Xb + (size_t)arow * FH + fq * 8;

    short8 a0 = *(const short8*)(ap + 0);
    short8 a1 = *(const short8*)(ap + 32);
    short8 a2 = *(const short8*)(ap + 64);
    short8 a3 = *(const short8*)(ap + 96);

    f32x4 acc[8] = {};

    auto proc = [&](int k0, short8 a) {
        int cb = k0 * 2 + fq * 16;
        #pragma unroll
        for (int c = 0; c < 8; ++c) {
            int lr = c * 16 + fr;
            unsigned addr = ((unsigned)(lr * 256 + cb)) ^ ((unsigned)(lr & 7) << 4);
            short8 bh = *(const short8*)((const char*)WhS + addr);
            short8 bl = *(const short8*)((const char*)WlS + addr);
            acc[c] = __builtin_amdgcn_mfma_f32_16x16x32_bf16(a, bh, acc[c], 0, 0, 0);
            acc[c] = __builtin_amdgcn_mfma_f32_16x16x32_bf16(a, bl, acc[c], 0, 0, 0);
        }
    };
    proc(0, a0);
    proc(32, a1);
    proc(64, a2);
    proc(96, a3);

    #pragma unroll
    for (int c = 0; c < 8; ++c) {
        float* outp = (c < 4) ? outA : outB;
        const float* bp = (c < 4) ? biasA : biasB;
        int col = (c & 3) * 16 + fr;
        float bv = bp[col];
        #pragma unroll
        for (int j = 0; j < 4; ++j) {
            int row = row0 + fq * 4 + j;
            if (row < M) outp[(size_t)row * FO + col] = acc[c][j] + bv;
        }
    }
}

// ---------------- launch ----------------

extern "C" void kernel_launch(void* const* d_in, const int* in_sizes, int n_in,
                              void* d_out, int out_size, void* d_ws, size_t ws_size,
                              hipStream_t stream) {
    const float* x   = (const float*)d_in[0];
    const int*   ei  = (const int*)d_in[1];
    const float* W1  = (const float*)d_in[2];
    const float* b1  = (const float*)d_in[3];
    const float* Wmu = (const float*)d_in[4];
    const float* bmu = (const float*)d_in[5];
    const float* Wlg = (const float*)d_in[6];
    const float* blg = (const float*)d_in[7];

    const int n = in_sizes[0] / FIN;   // 50000
    const int E = in_sizes[1] / 2;     // 800000
    const int* src = ei;
    const int* dst = ei + E;
    const int nstrips = (n + 15) / 16; // 3125

    char* ws = (char*)d_ws;
    size_t off = 0;
    auto alloc = [&](size_t bytes) -> void* {
        void* p = ws + off;
        off = (off + bytes + 255) & ~((size_t)255);
        return p;
    };
    int*   cnt    = (int*)  alloc((size_t)n * 4);
    int*   offs   = (int*)  alloc((size_t)(n + 1) * 4);
    int*   cursor = (int*)  alloc((size_t)n * 4);
    int*   bsum   = (int*)  alloc(1024);
    float* dinv   = (float*)alloc((size_t)n * 4);
    int2*  esort  = (int2*) alloc((size_t)E * 8);
    unsigned short* hbf  = (unsigned short*)alloc((size_t)n * FH * 2);  // bf16 h
    unsigned short* h1bf = (unsigned short*)alloc((size_t)n * FH * 2);  // bf16 h1
    unsigned short* ah2b = (unsigned short*)alloc((size_t)n * FH * 2);  // bf16 ah2
    unsigned short* W1b = (unsigned short*)alloc((size_t)FH * FIN * 2);
    unsigned short* W2h = (unsigned short*)alloc((size_t)FH * FH * 2);
    unsigned short* W2l = (unsigned short*)alloc((size_t)FH * FH * 2);

    hipMemsetAsync(cnt, 0, (size_t)n * 4, stream);
    hipMemsetAsync(cursor, 0, (size_t)n * 4, stream);

    // weight conversions (independent of graph work)
    convw1_kernel<<<(FH * FIN / 4 + 255) / 256, 256, 0, stream>>>(W1, W1b, FH * FIN / 4);
    convw2_kernel<<<(FH * FH + 255) / 256, 256, 0, stream>>>(Wmu, Wlg, W2h, W2l);

    count_kernel<<<(E + 255) / 256, 256, 0, stream>>>(dst, cnt, E);
    dinv_kernel<<<(n + 255) / 256, 256, 0, stream>>>(cnt, dinv, n);

    int nb = (n + 1023) / 1024;  // 49
    scan1_kernel<<<nb, 256, 0, stream>>>(cnt, offs, bsum, n);
    scan2_kernel<<<1, 256, 0, stream>>>(bsum, nb);
    scan3_kernel<<<(n + 255) / 256, 256, 0, stream>>>(offs, bsum, n, E);

    fill_kernel<<<(E + 255) / 256, 256, 0, stream>>>(src, dst, dinv, offs, cursor, esort, E);

    // layer 1: h = x @ W1^T   (bf16 MFMA, 1-barrier/K-step dbuf tile, bf16 out)
    gemm1_kernel<<<(n + 63) / 64, 256, 0, stream>>>(x, W1b, hbf, n);
    // h1 = relu(A_norm @ h + b1)  (bf16 gather table, bf16 out)
    spmm_kernel<<<(n + 3) / 4, 256, 0, stream>>>(
        (const unsigned*)hbf, offs, esort, dinv, b1, (unsigned*)h1bf, n, 1);
    // ah2 = A_norm @ h1  (bf16 gathers, bf16 out)
    spmm_kernel<<<(n + 3) / 4, 256, 0, stream>>>(
        (const unsigned*)h1bf, offs, esort, dinv, nullptr, (unsigned*)ah2b, n, 0);
    // mu / logstd = ah2b @ W^T + b   (bf16 A, hi/lo B, whole W2 in LDS)
    float* outmu = (float*)d_out;
    float* outlg = outmu + (size_t)n * FO;
    gemm2_kernel<<<512, 512, 0, stream>>>(ah2b, W2h, W2l, outmu, outlg, bmu, blg, n, nstrips);
}

// Round 7
// 197.701 us; speedup vs baseline: 1.7018x; 1.0659x over previous
//
#include <hip/hip_runtime.h>

constexpr int FIN = 512;
constexpr int FH  = 128;
constexpr int FO  = 64;

typedef short short8 __attribute__((ext_vector_type(8)));
typedef float f32x4 __attribute__((ext_vector_type(4)));

__device__ __forceinline__ unsigned short f2bf(float f) {
    unsigned u = __float_as_uint(f);
    u += 0x7fffu + ((u >> 16) & 1u);   // RNE
    return (unsigned short)(u >> 16);
}
__device__ __forceinline__ float bf2f(unsigned short h) {
    return __uint_as_float((unsigned)h << 16);
}
__device__ __forceinline__ float bflo(unsigned v) { return __uint_as_float(v << 16); }
__device__ __forceinline__ float bfhi(unsigned v) { return __uint_as_float(v & 0xffff0000u); }

// ---------------- fused pre-pass: count | convw1 | convw2 (block ranges) -----------
// blocks [0, cntB): count in-degrees; [cntB, cntB+64): convw1; [cntB+64, cntB+128): convw2

__global__ void pre_kernel(const int* __restrict__ dst, int* __restrict__ cnt, int E,
                           const float* __restrict__ W1, unsigned short* __restrict__ W1b,
                           const float* __restrict__ Wmu, const float* __restrict__ Wlg,
                           unsigned short* __restrict__ Wh, unsigned short* __restrict__ Wl,
                           int cntB) {
    int b = blockIdx.x;
    if (b < cntB) {
        int i = b * 256 + threadIdx.x;
        if (i < E) atomicAdd(&cnt[dst[i]], 1);
    } else if (b < cntB + 64) {
        int i = (b - cntB) * 256 + threadIdx.x;   // 0..16383 float4s
        float4 v = ((const float4*)W1)[i];
        ushort4 p;
        p.x = f2bf(v.x); p.y = f2bf(v.y); p.z = f2bf(v.z); p.w = f2bf(v.w);
        ((ushort4*)W1b)[i] = p;
    } else {
        int i = (b - cntB - 64) * 256 + threadIdx.x;  // 0..16383 elems
        int r = i >> 7, c = i & 127;
        float f = (r < 64) ? Wmu[r * 128 + c] : Wlg[(r - 64) * 128 + c];
        unsigned short h = f2bf(f);
        Wh[i] = h;
        Wl[i] = f2bf(f - bf2f(h));
    }
}

// ---------------- exclusive scan (3 kernels, 1024 elems/block) + fused dinv --------

__global__ void scan1_kernel(const int* __restrict__ cnt, int* __restrict__ offs,
                             int* __restrict__ bsum, float* __restrict__ dinv, int n) {
    __shared__ int sdata[256];
    int t = threadIdx.x;
    int base = blockIdx.x * 1024 + t * 4;
    int4 c = make_int4(0, 0, 0, 0);
    if (base + 3 < n) {
        c = *(const int4*)(cnt + base);
    } else {
        if (base + 0 < n) c.x = cnt[base + 0];
        if (base + 1 < n) c.y = cnt[base + 1];
        if (base + 2 < n) c.z = cnt[base + 2];
        if (base + 3 < n) c.w = cnt[base + 3];
    }
    // fused dinv = rsqrt(deg+1)
    if (base + 0 < n) dinv[base + 0] = rsqrtf((float)(c.x + 1));
    if (base + 1 < n) dinv[base + 1] = rsqrtf((float)(c.y + 1));
    if (base + 2 < n) dinv[base + 2] = rsqrtf((float)(c.z + 1));
    if (base + 3 < n) dinv[base + 3] = rsqrtf((float)(c.w + 1));

    int s0 = c.x + c.y + c.z + c.w;
    sdata[t] = s0;
    __syncthreads();
    for (int off = 1; off < 256; off <<= 1) {
        int v = (t >= off) ? sdata[t - off] : 0;
        __syncthreads();
        sdata[t] += v;
        __syncthreads();
    }
    int excl = sdata[t] - s0;
    if (t == 255) bsum[blockIdx.x] = sdata[255];
    if (base + 0 < n) offs[base + 0] = excl;
    if (base + 1 < n) offs[base + 1] = excl + c.x;
    if (base + 2 < n) offs[base + 2] = excl + c.x + c.y;
    if (base + 3 < n) offs[base + 3] = excl + c.x + c.y + c.z;
}

__global__ void scan2_kernel(int* __restrict__ bsum, int nb) {
    __shared__ int sdata[256];
    int t = threadIdx.x;
    int v = (t < nb) ? bsum[t] : 0;
    sdata[t] = v;
    __syncthreads();
    for (int off = 1; off < 256; off <<= 1) {
        int u = (t >= off) ? sdata[t - off] : 0;
        __syncthreads();
        sdata[t] += u;
        __syncthreads();
    }
    if (t < nb) bsum[t] = sdata[t] - v;  // exclusive
}

__global__ void scan3_kernel(int* __restrict__ offs, const int* __restrict__ bsum,
                             int n, int E) {
    int i = blockIdx.x * blockDim.x + threadIdx.x;
    if (i < n) offs[i] += bsum[i >> 10];
    if (i == 0) offs[n] = E;
}

// ---------------- CSR fill (counting sort by dst) ----------------

__global__ void fill_kernel(const int* __restrict__ src, const int* __restrict__ dst,
                            const float* __restrict__ dinv, const int* __restrict__ offs,
                            int* __restrict__ cursor, int2* __restrict__ esort, int E) {
    int i = blockIdx.x * blockDim.x + threadIdx.x;
    if (i < E) {
        int s = src[i];
        int d = dst[i];
        int pos = offs[d] + atomicAdd(&cursor[d], 1);
        float w = dinv[s] * dinv[d];
        esort[pos] = make_int2(s, __float_as_int(w));
    }
}

// ---------------- SpMM gather (bf16 table), unroll-8 for MLP ----------------------

__global__ void spmm_kernel(const unsigned int* __restrict__ hin, const int* __restrict__ offs,
                            const int2* __restrict__ esort, const float* __restrict__ dinv,
                            const float* __restrict__ bias, unsigned int* __restrict__ hout,
                            int n, int relu) {
    int gid = blockIdx.x * blockDim.x + threadIdx.x;
    int node = gid >> 6;            // one 64-lane wave per node
    int lane = threadIdx.x & 63;    // lane handles channels 2*lane, 2*lane+1
    if (node >= n) return;
    float di = dinv[node];
    unsigned hv = hin[(size_t)node * 64 + lane];
    float ax = di * di * bflo(hv);
    float ay = di * di * bfhi(hv);
    int p = offs[node];
    int end = offs[node + 1];
    // align p to even so int4 (2-edge) loads are 16B-aligned
    if ((p & 1) && p < end) {
        int2 e = esort[p];
        unsigned v = hin[(size_t)e.x * 64 + lane];
        float w = __int_as_float(e.y);
        ax = fmaf(w, bflo(v), ax); ay = fmaf(w, bfhi(v), ay);
        ++p;
    }
    for (; p + 8 <= end; p += 8) {
        int4 q0 = *(const int4*)(esort + p + 0);
        int4 q1 = *(const int4*)(esort + p + 2);
        int4 q2 = *(const int4*)(esort + p + 4);
        int4 q3 = *(const int4*)(esort + p + 6);
        unsigned v0 = hin[(size_t)q0.x * 64 + lane];
        unsigned v1 = hin[(size_t)q0.z * 64 + lane];
        unsigned v2 = hin[(size_t)q1.x * 64 + lane];
        unsigned v3 = hin[(size_t)q1.z * 64 + lane];
        unsigned v4 = hin[(size_t)q2.x * 64 + lane];
        unsigned v5 = hin[(size_t)q2.z * 64 + lane];
        unsigned v6 = hin[(size_t)q3.x * 64 + lane];
        unsigned v7 = hin[(size_t)q3.z * 64 + lane];
        float w0 = __int_as_float(q0.y), w1 = __int_as_float(q0.w);
        float w2 = __int_as_float(q1.y), w3 = __int_as_float(q1.w);
        float w4 = __int_as_float(q2.y), w5 = __int_as_float(q2.w);
        float w6 = __int_as_float(q3.y), w7 = __int_as_float(q3.w);
        ax = fmaf(w0, bflo(v0), ax); ay = fmaf(w0, bfhi(v0), ay);
        ax = fmaf(w1, bflo(v1), ax); ay = fmaf(w1, bfhi(v1), ay);
        ax = fmaf(w2, bflo(v2), ax); ay = fmaf(w2, bfhi(v2), ay);
        ax = fmaf(w3, bflo(v3), ax); ay = fmaf(w3, bfhi(v3), ay);
        ax = fmaf(w4, bflo(v4), ax); ay = fmaf(w4, bfhi(v4), ay);
        ax = fmaf(w5, bflo(v5), ax); ay = fmaf(w5, bfhi(v5), ay);
        ax = fmaf(w6, bflo(v6), ax); ay = fmaf(w6, bfhi(v6), ay);
        ax = fmaf(w7, bflo(v7), ax); ay = fmaf(w7, bfhi(v7), ay);
    }
    for (; p + 2 <= end; p += 2) {
        int4 q = *(const int4*)(esort + p);
        unsigned v0 = hin[(size_t)q.x * 64 + lane];
        unsigned v1 = hin[(size_t)q.z * 64 + lane];
        float w0 = __int_as_float(q.y), w1 = __int_as_float(q.w);
        ax = fmaf(w0, bflo(v0), ax); ay = fmaf(w0, bfhi(v0), ay);
        ax = fmaf(w1, bflo(v1), ax); ay = fmaf(w1, bfhi(v1), ay);
    }
    if (p < end) {
        int2 e = esort[p];
        unsigned v = hin[(size_t)e.x * 64 + lane];
        float w = __int_as_float(e.y);
        ax = fmaf(w, bflo(v), ax); ay = fmaf(w, bfhi(v), ay);
    }
    if (bias) {
        float2 b = ((const float2*)bias)[lane];
        ax += b.x; ay += b.y;
    }
    if (relu) { ax = fmaxf(ax, 0.f); ay = fmaxf(ay, 0.f); }
    unsigned o = (unsigned)f2bf(ax) | ((unsigned)f2bf(ay) << 16);
    hout[(size_t)node * 64 + lane] = o;
}

// ---------------- GEMM1: h[M,128](bf16) = X[M,512] @ W1b[128,512]^T ----------------
// Persistent whole-W1 in LDS (128KB, swizzled), one block of 1024 thr per CU.
// One prologue barrier; then each of 16 waves independently streams a 16-row strip
// of X (reg A + cvt, depth-1 prefetch) against LDS B. ZERO steady-state barriers.

__global__ __launch_bounds__(1024, 4) void gemm1_kernel(
    const float* __restrict__ X, const unsigned short* __restrict__ Wb,
    unsigned short* __restrict__ out, int M, int nstrips) {
    extern __shared__ __align__(16) unsigned short Bs[];   // 128 KB
    int tid = threadIdx.x;

    // stage all of W1b swizzled: 8192 16B-chunks, 1024 thr x 8
    #pragma unroll
    for (int j = 0; j < 8; ++j) {
        int f = tid + j * 1024;             // chunk id
        int row = f >> 6;                   // 64 chunks (1024B) per row
        unsigned addr = ((unsigned)f << 4) ^ ((unsigned)(row & 7) << 4);
        *(short8*)((char*)Bs + addr) = ((const short8*)Wb)[f];
    }
    __syncthreads();

    int lane = tid & 63, wid = tid >> 6;    // wid 0..15
    int fr = lane & 15, fq = lane >> 4;
    int s = blockIdx.x * 16 + wid;
    if (s >= nstrips) return;
    int row0 = s * 16;
    int arow = row0 + fr; if (arow >= M) arow = M - 1;
    const float* ap = X + (size_t)arow * FIN + fq * 8;

    f32x4 acc[8] = {};

    float4 c0 = *(const float4*)(ap + 0);
    float4 c1 = *(const float4*)(ap + 4);
    float4 c2 = *(const float4*)(ap + 32);
    float4 c3 = *(const float4*)(ap + 36);

    #pragma unroll
    for (int kk = 0; kk < 8; ++kk) {
        int k0 = kk * 64;
        float4 d0 = c0, d1 = c1, d2 = c2, d3 = c3;
        if (kk < 7) {
            c0 = *(const float4*)(ap + k0 + 64);
            c1 = *(const float4*)(ap + k0 + 68);
            c2 = *(const float4*)(ap + k0 + 96);
            c3 = *(const float4*)(ap + k0 + 100);
        }
        short8 af0, af1;
        af0[0] = (short)f2bf(d0.x); af0[1] = (short)f2bf(d0.y);
        af0[2] = (short)f2bf(d0.z); af0[3] = (short)f2bf(d0.w);
        af0[4] = (short)f2bf(d1.x); af0[5] = (short)f2bf(d1.y);
        af0[6] = (short)f2bf(d1.z); af0[7] = (short)f2bf(d1.w);
        af1[0] = (short)f2bf(d2.x); af1[1] = (short)f2bf(d2.y);
        af1[2] = (short)f2bf(d2.z); af1[3] = (short)f2bf(d2.w);
        af1[4] = (short)f2bf(d3.x); af1[5] = (short)f2bf(d3.y);
        af1[6] = (short)f2bf(d3.z); af1[7] = (short)f2bf(d3.w);

        int cb0 = k0 * 2 + fq * 16;
        #pragma unroll
        for (int c = 0; c < 8; ++c) {
            int br = c * 16 + fr;
            short8 b0 = *(const short8*)((const char*)Bs + br * 1024 +
                                         ((unsigned)cb0 ^ ((unsigned)(br & 7) << 4)));
            acc[c] = __builtin_amdgcn_mfma_f32_16x16x32_bf16(af0, b0, acc[c], 0, 0, 0);
        }
        int cb1 = cb0 + 64;
        #pragma unroll
        for (int c = 0; c < 8; ++c) {
            int br = c * 16 + fr;
            short8 b1 = *(const short8*)((const char*)Bs + br * 1024 +
                                         ((unsigned)cb1 ^ ((unsigned)(br & 7) << 4)));
            acc[c] = __builtin_amdgcn_mfma_f32_16x16x32_bf16(af1, b1, acc[c], 0, 0, 0);
        }
    }

    // store bf16: col = c*16+fr, row = row0 + fq*4 + j
    #pragma unroll
    for (int c = 0; c < 8; ++c) {
        #pragma unroll
        for (int j = 0; j < 4; ++j) {
            int row = row0 + fq * 4 + j;
            if (row < M) out[(size_t)row * FH + c * 16 + fr] = f2bf(acc[c][j]);
        }
    }
}

// ---------------- GEMM2: mu/logstd[M,64] = ah2b[M,128](bf16) @ W^T + b ------------
// A is bf16 (no split); B split hi/lo -> 2 MFMA per fragment (~fp32 weight fidelity).
// Whole W2 (hi+lo bf16, 64KB) in LDS. 512 blocks x 8 waves: every wave <=1 strip.

__global__ __launch_bounds__(512) void gemm2_kernel(
    const unsigned short* __restrict__ Xb,
    const unsigned short* __restrict__ Wh, const unsigned short* __restrict__ Wl,
    float* __restrict__ outA, float* __restrict__ outB,
    const float* __restrict__ biasA, const float* __restrict__ biasB,
    int M, int nstrips) {
    __shared__ __align__(16) unsigned short WhS[128 * 128];  // 32KB
    __shared__ __align__(16) unsigned short WlS[128 * 128];  // 32KB
    int tid = threadIdx.x;

    #pragma unroll
    for (int j = 0; j < 4; ++j) {
        int f = tid + j * 512;              // 16B chunk id, 0..2047
        int row = f >> 4;                   // 16 chunks per row
        unsigned addr = ((unsigned)f * 16u) ^ ((unsigned)(row & 7) << 4);
        *(short8*)((char*)WhS + addr) = ((const short8*)Wh)[f];
        *(short8*)((char*)WlS + addr) = ((const short8*)Wl)[f];
    }
    __syncthreads();

    int lane = tid & 63, wid = tid >> 6;
    int fr = lane & 15, fq = lane >> 4;
    int s = blockIdx.x * 8 + wid;
    if (s >= nstrips) return;
    int row0 = s * 16;
    int arow = row0 + fr; if (arow > M - 1) arow = M - 1;
    const unsigned short* ap = Xb + (size_t)arow * FH + fq * 8;

    short8 a0 = *(const short8*)(ap + 0);
    short8 a1 = *(const short8*)(ap + 32);
    short8 a2 = *(const short8*)(ap + 64);
    short8 a3 = *(const short8*)(ap + 96);

    f32x4 acc[8] = {};

    auto proc = [&](int k0, short8 a) {
        int cb = k0 * 2 + fq * 16;
        #pragma unroll
        for (int c = 0; c < 8; ++c) {
            int lr = c * 16 + fr;
            unsigned addr = ((unsigned)(lr * 256 + cb)) ^ ((unsigned)(lr & 7) << 4);
            short8 bh = *(const short8*)((const char*)WhS + addr);
            short8 bl = *(const short8*)((const char*)WlS + addr);
            acc[c] = __builtin_amdgcn_mfma_f32_16x16x32_bf16(a, bh, acc[c], 0, 0, 0);
            acc[c] = __builtin_amdgcn_mfma_f32_16x16x32_bf16(a, bl, acc[c], 0, 0, 0);
        }
    };
    proc(0, a0);
    proc(32, a1);
    proc(64, a2);
    proc(96, a3);

    #pragma unroll
    for (int c = 0; c < 8; ++c) {
        float* outp = (c < 4) ? outA : outB;
        const float* bp = (c < 4) ? biasA : biasB;
        int col = (c & 3) * 16 + fr;
        float bv = bp[col];
        #pragma unroll
        for (int j = 0; j < 4; ++j) {
            int row = row0 + fq * 4 + j;
            if (row < M) outp[(size_t)row * FO + col] = acc[c][j] + bv;
        }
    }
}

// ---------------- launch ----------------

extern "C" void kernel_launch(void* const* d_in, const int* in_sizes, int n_in,
                              void* d_out, int out_size, void* d_ws, size_t ws_size,
                              hipStream_t stream) {
    const float* x   = (const float*)d_in[0];
    const int*   ei  = (const int*)d_in[1];
    const float* W1  = (const float*)d_in[2];
    const float* b1  = (const float*)d_in[3];
    const float* Wmu = (const float*)d_in[4];
    const float* bmu = (const float*)d_in[5];
    const float* Wlg = (const float*)d_in[6];
    const float* blg = (const float*)d_in[7];

    const int n = in_sizes[0] / FIN;   // 50000
    const int E = in_sizes[1] / 2;     // 800000
    const int* src = ei;
    const int* dst = ei + E;
    const int nstrips = (n + 15) / 16; // 3125

    char* ws = (char*)d_ws;
    size_t off = 0;
    auto alloc = [&](size_t bytes) -> void* {
        void* p = ws + off;
        off = (off + bytes + 255) & ~((size_t)255);
        return p;
    };
    int*   cnt    = (int*)  alloc((size_t)n * 4);
    int*   offs   = (int*)  alloc((size_t)(n + 1) * 4);
    int*   cursor = (int*)  alloc((size_t)n * 4);
    int*   bsum   = (int*)  alloc(1024);
    float* dinv   = (float*)alloc((size_t)n * 4);
    int2*  esort  = (int2*) alloc((size_t)E * 8);
    unsigned short* hbf  = (unsigned short*)alloc((size_t)n * FH * 2);  // bf16 h
    unsigned short* h1bf = (unsigned short*)alloc((size_t)n * FH * 2);  // bf16 h1
    unsigned short* ah2b = (unsigned short*)alloc((size_t)n * FH * 2);  // bf16 ah2
    unsigned short* W1b = (unsigned short*)alloc((size_t)FH * FIN * 2);
    unsigned short* W2h = (unsigned short*)alloc((size_t)FH * FH * 2);
    unsigned short* W2l = (unsigned short*)alloc((size_t)FH * FH * 2);

    hipMemsetAsync(cnt, 0, (size_t)n * 4, stream);
    hipMemsetAsync(cursor, 0, (size_t)n * 4, stream);

    // fused: count + convw1 + convw2
    int cntB = (E + 255) / 256;  // 3125
    pre_kernel<<<cntB + 128, 256, 0, stream>>>(dst, cnt, E, W1, W1b, Wmu, Wlg, W2h, W2l, cntB);

    int nb = (n + 1023) / 1024;  // 49
    scan1_kernel<<<nb, 256, 0, stream>>>(cnt, offs, bsum, dinv, n);
    scan2_kernel<<<1, 256, 0, stream>>>(bsum, nb);
    scan3_kernel<<<(n + 255) / 256, 256, 0, stream>>>(offs, bsum, n, E);

    fill_kernel<<<(E + 255) / 256, 256, 0, stream>>>(src, dst, dinv, offs, cursor, esort, E);

    // layer 1: h = x @ W1^T   (whole W1 in 128KB LDS, barrier-free steady state)
    gemm1_kernel<<<(nstrips + 15) / 16, 1024, 128 * 1024, stream>>>(x, W1b, hbf, n, nstrips);
    // h1 = relu(A_norm @ h + b1)
    spmm_kernel<<<(n + 3) / 4, 256, 0, stream>>>(
        (const unsigned*)hbf, offs, esort, dinv, b1, (unsigned*)h1bf, n, 1);
    // ah2 = A_norm @ h1
    spmm_kernel<<<(n + 3) / 4, 256, 0, stream>>>(
        (const unsigned*)h1bf, offs, esort, dinv, nullptr, (unsigned*)ah2b, n, 0);
    // mu / logstd = ah2b @ W^T + b
    float* outmu = (float*)d_out;
    float* outlg = outmu + (size_t)n * FO;
    gemm2_kernel<<<512, 512, 0, stream>>>(ah2b, W2h, W2l, outmu, outlg, bmu, blg, n, nstrips);
}